// Round 6
// baseline (291.046 us; speedup 1.0000x reference)
//
#include <hip/hip_runtime.h>
#include <hip/hip_bf16.h>

#define N_NODES 50000
#define N_EDGES 800000
#define EMB 100
#define HALF_EMB 50
#define QEMB 25                        // EMB/4 : row = 25 x ushort4 (bf16) or 25 x float4
#define NORM_EPS 1e-12f
#define BROWS 64                       // rows per bucket
#define NB ((N_NODES + BROWS - 1) / BROWS)   // 782 buckets
#define CAP 2048                       // slab capacity per bucket (avg fill ~1023)
#define EPB 1024                       // edges per partition block

__device__ inline float4 bf4_to_f4(ushort4 p) {
    float4 r;
    r.x = __uint_as_float((unsigned)p.x << 16);
    r.y = __uint_as_float((unsigned)p.y << 16);
    r.z = __uint_as_float((unsigned)p.z << 16);
    r.w = __uint_as_float((unsigned)p.w << 16);
    return r;
}

__device__ inline unsigned short f_to_bf(float f) {
    __hip_bfloat16 h = __float2bfloat16(f);
    return *reinterpret_cast<unsigned short*>(&h);
}

// Pass 1: block-level radix partition into NB coarse buckets (782 blocks).
__global__ void bucket_scatter(const int* __restrict__ adj_row,
                               const int* __restrict__ adj_col,
                               const float* __restrict__ adj_val,
                               int* __restrict__ bucket_cnt,
                               int2* __restrict__ slab) {
    __shared__ int hist[NB];
    __shared__ int gbase[NB];
    __shared__ int lcur[NB];
    const int t = threadIdx.x;
    const int base_e = blockIdx.x * EPB;
    for (int i = t; i < NB; i += 256) { hist[i] = 0; lcur[i] = 0; }
    __syncthreads();
    int rows[EPB / 256];
    #pragma unroll
    for (int j = 0; j < EPB / 256; ++j) {
        int e = base_e + j * 256 + t;
        int r = (e < N_EDGES) ? adj_row[e] : -1;
        rows[j] = r;
        if (r >= 0) atomicAdd(&hist[r / BROWS], 1);
    }
    __syncthreads();
    for (int i = t; i < NB; i += 256) {
        int c = hist[i];
        gbase[i] = (c > 0) ? atomicAdd(&bucket_cnt[i], c) : 0;
    }
    __syncthreads();
    #pragma unroll
    for (int j = 0; j < EPB / 256; ++j) {
        int e = base_e + j * 256 + t;
        int r = rows[j];
        if (r >= 0) {
            int b = r / BROWS;
            int p = atomicAdd(&lcur[b], 1);
            unsigned rc = ((unsigned)r << 16) | (unsigned)adj_col[e];
            slab[(size_t)b * CAP + gbase[b] + p] =
                make_int2((int)rc, __float_as_int(adj_val[e]));
        }
    }
}

// Pass 2: exclusive scan of NB bucket counts (single block of 1024).
__global__ void scan_buckets(const int* __restrict__ bucket_cnt,
                             int* __restrict__ bucket_base,
                             int* __restrict__ row_ptr) {
    __shared__ int s[1024];
    int t = threadIdx.x;
    int v = (t < NB) ? bucket_cnt[t] : 0;
    s[t] = v;
    __syncthreads();
    #pragma unroll
    for (int off = 1; off < 1024; off <<= 1) {
        int n = (t >= off) ? s[t - off] : 0;
        __syncthreads();
        s[t] += n;
        __syncthreads();
    }
    if (t < NB) bucket_base[t] = s[t] - v;
    if (t == 0) row_ptr[N_NODES] = N_EDGES;
}

// Pass 3: per-bucket counting sort in LDS -> exact CSR + row_ptr (782 blocks).
__global__ void csr_build(const int* __restrict__ bucket_cnt,
                          const int* __restrict__ bucket_base,
                          const int2* __restrict__ slab,
                          int2* __restrict__ csr_cv,
                          int* __restrict__ row_ptr) {
    __shared__ int2 eds[CAP];
    __shared__ int hist[BROWS];   // later reused as scatter cursor
    __shared__ int incl[BROWS];
    const int b = blockIdx.x, t = threadIdx.x;
    const int cnt = bucket_cnt[b];
    const int base = bucket_base[b];
    for (int i = t; i < cnt; i += 256) eds[i] = slab[(size_t)b * CAP + i];
    if (t < BROWS) hist[t] = 0;
    __syncthreads();
    for (int i = t; i < cnt; i += 256)
        atomicAdd(&hist[(int)(((unsigned)eds[i].x) >> 16) & (BROWS - 1)], 1);
    __syncthreads();
    int v = (t < BROWS) ? hist[t] : 0;
    if (t < BROWS) incl[t] = v;
    __syncthreads();
    #pragma unroll
    for (int off = 1; off < BROWS; off <<= 1) {
        int n = (t >= off && t < BROWS) ? incl[t - off] : 0;
        __syncthreads();
        if (t < BROWS) incl[t] += n;
        __syncthreads();
    }
    int ex = (t < BROWS) ? (incl[t] - v) : 0;
    __syncthreads();
    if (t < BROWS) hist[t] = ex;          // cursor init
    int gr = b * BROWS + t;
    if (t < BROWS && gr < N_NODES) row_ptr[gr] = base + ex;
    __syncthreads();
    for (int i = t; i < cnt; i += 256) {
        int2 e = eds[i];
        int l = (int)(((unsigned)e.x) >> 16) & (BROWS - 1);
        int p = atomicAdd(&hist[l], 1);
        csr_cv[base + p] = e;
    }
}

// Emb prep: xbE = bf16(emb), norm0[node] = ||emb_row||. No out access.
__global__ void conv_emb(const float* __restrict__ emb, float* __restrict__ norm0,
                         __hip_bfloat162* __restrict__ xb) {
    int wave = blockIdx.x * (blockDim.x >> 6) + (threadIdx.x >> 6);
    int lane = threadIdx.x & 63;
    if (wave >= N_NODES) return;
    float2 v = make_float2(0.0f, 0.0f);
    size_t idx = (size_t)wave * HALF_EMB + lane;
    if (lane < HALF_EMB) v = ((const float2*)emb)[idx];
    float s = v.x * v.x + v.y * v.y;
    #pragma unroll
    for (int off = 32; off > 0; off >>= 1) s += __shfl_xor(s, off);
    if (lane == 0) norm0[wave] = sqrtf(s);
    if (lane < HALF_EMB) {
        __hip_bfloat162 b;
        b.x = __float2bfloat16(v.x);
        b.y = __float2bfloat16(v.y);
        xb[idx] = b;
    }
}

// SpMM: bf16 gather (half-wave ushort4 lanes), fp32 accumulate.
// Non-final: write raw bf16 y + per-node norm.
// Final: out = a0*emb/n0 + a1*x1/n1 + a2*x2/n2 + a3*acc/n3.
__global__ void spmm_fused(const int* __restrict__ row_ptr,
                           const int2* __restrict__ csr_cv,
                           const ushort4* __restrict__ xb,
                           ushort4* __restrict__ yb,
                           float* __restrict__ norm_out,
                           const float* __restrict__ a,
                           const float* __restrict__ emb,
                           const ushort4* __restrict__ xb1,
                           const ushort4* __restrict__ xb2,
                           const float* __restrict__ norms,
                           float* __restrict__ out,
                           int final_layer) {
    int wave = blockIdx.x * (blockDim.x >> 6) + (threadIdx.x >> 6);
    int lane = threadIdx.x & 63;
    int h = lane >> 5, c = lane & 31;
    if (wave >= N_NODES) return;
    int start = row_ptr[wave];
    int end   = row_ptr[wave + 1];
    bool act = (c < QEMB);
    float4 acc = make_float4(0.0f, 0.0f, 0.0f, 0.0f);
    int e = start;
    for (; e + 3 < end; e += 4) {
        int2 cv0 = csr_cv[e];
        int2 cv1 = csr_cv[e + 1];
        int2 cv2 = csr_cv[e + 2];
        int2 cv3 = csr_cv[e + 3];
        int2 ca = h ? cv1 : cv0;
        int2 cb = h ? cv3 : cv2;
        if (act) {
            ushort4 pa = xb[(size_t)(ca.x & 0xFFFF) * QEMB + c];
            ushort4 pb = xb[(size_t)(cb.x & 0xFFFF) * QEMB + c];
            float va = __int_as_float(ca.y), vb = __int_as_float(cb.y);
            float4 fa = bf4_to_f4(pa), fb = bf4_to_f4(pb);
            acc.x += va * fa.x + vb * fb.x;
            acc.y += va * fa.y + vb * fb.y;
            acc.z += va * fa.z + vb * fb.z;
            acc.w += va * fa.w + vb * fb.w;
        }
    }
    for (; e < end; e += 2) {
        int2 cva = csr_cv[e];
        int2 cvb = (e + 1 < end) ? csr_cv[e + 1] : cva;
        int2 cv = h ? cvb : cva;
        float v = __int_as_float(cv.y);
        if (h && e + 1 >= end) v = 0.0f;
        if (act) {
            ushort4 p = xb[(size_t)(cv.x & 0xFFFF) * QEMB + c];
            float4 f = bf4_to_f4(p);
            acc.x += v * f.x;
            acc.y += v * f.y;
            acc.z += v * f.z;
            acc.w += v * f.w;
        }
    }
    // cross-half reduce: both halves end with the full row sums
    acc.x += __shfl_xor(acc.x, 32);
    acc.y += __shfl_xor(acc.y, 32);
    acc.z += __shfl_xor(acc.z, 32);
    acc.w += __shfl_xor(acc.w, 32);
    // sum of squares (count only h==0 lanes to avoid double count)
    float s = 0.0f;
    if (h == 0 && act)
        s = acc.x * acc.x + acc.y * acc.y + acc.z * acc.z + acc.w * acc.w;
    #pragma unroll
    for (int off = 32; off > 0; off >>= 1) s += __shfl_xor(s, off);
    if (!final_layer) {
        if (h == 0 && act) {
            ushort4 o;
            o.x = f_to_bf(acc.x);
            o.y = f_to_bf(acc.y);
            o.z = f_to_bf(acc.z);
            o.w = f_to_bf(acc.w);
            yb[(size_t)wave * QEMB + c] = o;
        }
        if (lane == 0) norm_out[wave] = sqrtf(s);
    } else {
        float s0 = a[0] / fmaxf(norms[wave], NORM_EPS);
        float s1 = a[1] / fmaxf(norms[N_NODES + wave], NORM_EPS);
        float s2 = a[2] / fmaxf(norms[2 * N_NODES + wave], NORM_EPS);
        float s3 = a[3] / fmaxf(sqrtf(s), NORM_EPS);
        if (h == 0 && act) {
            size_t idx = (size_t)wave * QEMB + c;
            float4 em = ((const float4*)emb)[idx];
            float4 f1 = bf4_to_f4(xb1[idx]);
            float4 f2 = bf4_to_f4(xb2[idx]);
            float4 o;
            o.x = s0 * em.x + s1 * f1.x + s2 * f2.x + s3 * acc.x;
            o.y = s0 * em.y + s1 * f1.y + s2 * f2.y + s3 * acc.y;
            o.z = s0 * em.z + s1 * f1.z + s2 * f2.z + s3 * acc.z;
            o.w = s0 * em.w + s1 * f1.w + s2 * f2.w + s3 * acc.w;
            ((float4*)out)[idx] = o;
        }
    }
}

extern "C" void kernel_launch(void* const* d_in, const int* in_sizes, int n_in,
                              void* d_out, int out_size, void* d_ws, size_t ws_size,
                              hipStream_t stream) {
    const int*   adj_row   = (const int*)d_in[0];
    const int*   adj_col   = (const int*)d_in[1];
    const float* adj_val   = (const float*)d_in[2];
    const float* embedding = (const float*)d_in[3];
    const float* a         = (const float*)d_in[4];
    float* out = (float*)d_out;

    // workspace layout. xb2 overlays slab (slab dead after csr_build,
    // xb2 first written in layer-2 spmm — stream-ordered, safe).
    int2* slab   = (int2*)d_ws;                                    // NB*CAP int2 = 12.8 MB
    int2* csr_cv = slab + (size_t)NB * CAP;                        // 800,000 int2
    ushort4* xbE = (ushort4*)(csr_cv + N_EDGES);                   // 50,000*25 = 10 MB
    ushort4* xb1 = xbE + (size_t)N_NODES * QEMB;                   // 10 MB
    float* norms = (float*)(xb1 + (size_t)N_NODES * QEMB);         // 3*50,000
    int* row_ptr     = (int*)(norms + 3 * N_NODES);                // 50,001
    int* bucket_cnt  = row_ptr + (N_NODES + 1);                    // NB
    int* bucket_base = bucket_cnt + NB;                            // NB
    ushort4* xb2 = (ushort4*)slab;                                 // overlay

    const int node_blocks = (N_NODES + 3) / 4;          // 4 waves / block
    const int part_blocks = (N_EDGES + EPB - 1) / EPB;  // 782

    // ---- CSR build: partition -> scan -> per-bucket sort ----
    hipMemsetAsync(bucket_cnt, 0, sizeof(int) * NB, stream);
    bucket_scatter<<<part_blocks, 256, 0, stream>>>(adj_row, adj_col, adj_val,
                                                    bucket_cnt, slab);
    scan_buckets<<<1, 1024, 0, stream>>>(bucket_cnt, bucket_base, row_ptr);
    csr_build<<<NB, 256, 0, stream>>>(bucket_cnt, bucket_base, slab, csr_cv, row_ptr);

    // ---- emb prep ----
    conv_emb<<<node_blocks, 256, 0, stream>>>(embedding, norms, (__hip_bfloat162*)xbE);

    // ---- layer 1, 2 (raw bf16 + norm), layer 3 (fused epilogue) ----
    spmm_fused<<<node_blocks, 256, 0, stream>>>(row_ptr, csr_cv, xbE, xb1,
                                                norms + N_NODES, a,
                                                nullptr, nullptr, nullptr, nullptr,
                                                nullptr, 0);
    spmm_fused<<<node_blocks, 256, 0, stream>>>(row_ptr, csr_cv, xb1, xb2,
                                                norms + 2 * N_NODES, a,
                                                nullptr, nullptr, nullptr, nullptr,
                                                nullptr, 0);
    spmm_fused<<<node_blocks, 256, 0, stream>>>(row_ptr, csr_cv, xb2, nullptr,
                                                nullptr, a,
                                                embedding, xb1, xb2, norms,
                                                out, 1);
}

// Round 7
// 268.785 us; speedup vs baseline: 1.0828x; 1.0828x over previous
//
#include <hip/hip_runtime.h>
#include <hip/hip_bf16.h>

#define N_NODES 50000
#define N_EDGES 800000
#define EMB 100
#define HALF_EMB 50
#define NORM_EPS 1e-12f
#define BROWS 64                       // rows per bucket
#define NB ((N_NODES + BROWS - 1) / BROWS)   // 782 buckets
#define CAP 2048                       // slab capacity per bucket (avg fill ~1023)
#define EPB 1024                       // edges per partition block

// Pass 1: block-level radix partition into NB coarse buckets (782 blocks).
__global__ void bucket_scatter(const int* __restrict__ adj_row,
                               const int* __restrict__ adj_col,
                               const float* __restrict__ adj_val,
                               int* __restrict__ bucket_cnt,
                               int2* __restrict__ slab) {
    __shared__ int hist[NB];
    __shared__ int gbase[NB];
    __shared__ int lcur[NB];
    const int t = threadIdx.x;
    const int base_e = blockIdx.x * EPB;
    for (int i = t; i < NB; i += 256) { hist[i] = 0; lcur[i] = 0; }
    __syncthreads();
    int rows[EPB / 256];
    #pragma unroll
    for (int j = 0; j < EPB / 256; ++j) {
        int e = base_e + j * 256 + t;
        int r = (e < N_EDGES) ? adj_row[e] : -1;
        rows[j] = r;
        if (r >= 0) atomicAdd(&hist[r / BROWS], 1);
    }
    __syncthreads();
    for (int i = t; i < NB; i += 256) {
        int c = hist[i];
        gbase[i] = (c > 0) ? atomicAdd(&bucket_cnt[i], c) : 0;
    }
    __syncthreads();
    #pragma unroll
    for (int j = 0; j < EPB / 256; ++j) {
        int e = base_e + j * 256 + t;
        int r = rows[j];
        if (r >= 0) {
            int b = r / BROWS;
            int p = atomicAdd(&lcur[b], 1);
            unsigned rc = ((unsigned)r << 16) | (unsigned)adj_col[e];
            slab[(size_t)b * CAP + gbase[b] + p] =
                make_int2((int)rc, __float_as_int(adj_val[e]));
        }
    }
}

// Pass 2: exclusive scan of NB bucket counts (single block of 1024).
__global__ void scan_buckets(const int* __restrict__ bucket_cnt,
                             int* __restrict__ bucket_base,
                             int* __restrict__ row_ptr) {
    __shared__ int s[1024];
    int t = threadIdx.x;
    int v = (t < NB) ? bucket_cnt[t] : 0;
    s[t] = v;
    __syncthreads();
    #pragma unroll
    for (int off = 1; off < 1024; off <<= 1) {
        int n = (t >= off) ? s[t - off] : 0;
        __syncthreads();
        s[t] += n;
        __syncthreads();
    }
    if (t < NB) bucket_base[t] = s[t] - v;
    if (t == 0) row_ptr[N_NODES] = N_EDGES;
}

// Pass 3: per-bucket counting sort in LDS -> exact CSR + row_ptr (782 blocks).
__global__ void csr_build(const int* __restrict__ bucket_cnt,
                          const int* __restrict__ bucket_base,
                          const int2* __restrict__ slab,
                          int2* __restrict__ csr_cv,
                          int* __restrict__ row_ptr) {
    __shared__ int2 eds[CAP];
    __shared__ int hist[BROWS];   // later reused as scatter cursor
    __shared__ int incl[BROWS];
    const int b = blockIdx.x, t = threadIdx.x;
    const int cnt = bucket_cnt[b];
    const int base = bucket_base[b];
    for (int i = t; i < cnt; i += 256) eds[i] = slab[(size_t)b * CAP + i];
    if (t < BROWS) hist[t] = 0;
    __syncthreads();
    for (int i = t; i < cnt; i += 256)
        atomicAdd(&hist[(int)(((unsigned)eds[i].x) >> 16) & (BROWS - 1)], 1);
    __syncthreads();
    int v = (t < BROWS) ? hist[t] : 0;
    if (t < BROWS) incl[t] = v;
    __syncthreads();
    #pragma unroll
    for (int off = 1; off < BROWS; off <<= 1) {
        int n = (t >= off && t < BROWS) ? incl[t - off] : 0;
        __syncthreads();
        if (t < BROWS) incl[t] += n;
        __syncthreads();
    }
    int ex = (t < BROWS) ? (incl[t] - v) : 0;
    __syncthreads();
    if (t < BROWS) hist[t] = ex;          // cursor init
    int gr = b * BROWS + t;
    if (t < BROWS && gr < N_NODES) row_ptr[gr] = base + ex;
    __syncthreads();
    for (int i = t; i < cnt; i += 256) {
        int2 e = eds[i];
        int l = (int)(((unsigned)e.x) >> 16) & (BROWS - 1);
        int p = atomicAdd(&hist[l], 1);
        csr_cv[base + p] = e;
    }
}

// Emb prep: xbE = bf16(emb), norm0[node] = ||emb_row||. No out access.
__global__ void conv_emb(const float* __restrict__ emb, float* __restrict__ norm0,
                         __hip_bfloat162* __restrict__ xb) {
    int wave = blockIdx.x * (blockDim.x >> 6) + (threadIdx.x >> 6);
    int lane = threadIdx.x & 63;
    if (wave >= N_NODES) return;
    float2 v = make_float2(0.0f, 0.0f);
    size_t idx = (size_t)wave * HALF_EMB + lane;
    if (lane < HALF_EMB) v = ((const float2*)emb)[idx];
    float s = v.x * v.x + v.y * v.y;
    #pragma unroll
    for (int off = 32; off > 0; off >>= 1) s += __shfl_xor(s, off);
    if (lane == 0) norm0[wave] = sqrtf(s);
    if (lane < HALF_EMB) {
        __hip_bfloat162 b;
        b.x = __float2bfloat16(v.x);
        b.y = __float2bfloat16(v.y);
        xb[idx] = b;
    }
}

// SpMM: full-wave bf16 gather (R5-proven shape), fp32 accumulate.
// Non-final: write raw bf16 y + per-node norm. No `out` access.
// Final: out = a0*emb/n0 + a1*x1/n1 + a2*x2/n2 + a3*acc/n3.
__global__ void spmm_fused(const int* __restrict__ row_ptr,
                           const int2* __restrict__ csr_cv,
                           const __hip_bfloat162* __restrict__ xb,
                           __hip_bfloat162* __restrict__ yb,
                           float* __restrict__ norm_out,
                           const float* __restrict__ a,
                           const float* __restrict__ emb,
                           const __hip_bfloat162* __restrict__ xb1,
                           const __hip_bfloat162* __restrict__ xb2,
                           const float* __restrict__ norms,
                           float* __restrict__ out,
                           int final_layer) {
    int wave = blockIdx.x * (blockDim.x >> 6) + (threadIdx.x >> 6);
    int lane = threadIdx.x & 63;
    if (wave >= N_NODES) return;
    int start = row_ptr[wave];
    int end   = row_ptr[wave + 1];
    bool act = (lane < HALF_EMB);
    float ax = 0.0f, ay = 0.0f;
    int e = start;
    for (; e + 3 < end; e += 4) {
        int2 cv0 = csr_cv[e];
        int2 cv1 = csr_cv[e + 1];
        int2 cv2 = csr_cv[e + 2];
        int2 cv3 = csr_cv[e + 3];
        if (act) {
            __hip_bfloat162 p0 = xb[(size_t)(cv0.x & 0xFFFF) * HALF_EMB + lane];
            __hip_bfloat162 p1 = xb[(size_t)(cv1.x & 0xFFFF) * HALF_EMB + lane];
            __hip_bfloat162 p2 = xb[(size_t)(cv2.x & 0xFFFF) * HALF_EMB + lane];
            __hip_bfloat162 p3 = xb[(size_t)(cv3.x & 0xFFFF) * HALF_EMB + lane];
            float v0 = __int_as_float(cv0.y), v1 = __int_as_float(cv1.y);
            float v2 = __int_as_float(cv2.y), v3 = __int_as_float(cv3.y);
            ax += v0 * __bfloat162float(p0.x); ay += v0 * __bfloat162float(p0.y);
            ax += v1 * __bfloat162float(p1.x); ay += v1 * __bfloat162float(p1.y);
            ax += v2 * __bfloat162float(p2.x); ay += v2 * __bfloat162float(p2.y);
            ax += v3 * __bfloat162float(p3.x); ay += v3 * __bfloat162float(p3.y);
        }
    }
    for (; e < end; ++e) {
        int2 cv = csr_cv[e];
        if (act) {
            __hip_bfloat162 p = xb[(size_t)(cv.x & 0xFFFF) * HALF_EMB + lane];
            float v = __int_as_float(cv.y);
            ax += v * __bfloat162float(p.x);
            ay += v * __bfloat162float(p.y);
        }
    }
    float s = ax * ax + ay * ay;
    #pragma unroll
    for (int off = 32; off > 0; off >>= 1) s += __shfl_xor(s, off);
    if (!final_layer) {
        if (act) {
            size_t idx = (size_t)wave * HALF_EMB + lane;
            __hip_bfloat162 bb;
            bb.x = __float2bfloat16(ax);
            bb.y = __float2bfloat16(ay);
            yb[idx] = bb;
        }
        if (lane == 0) norm_out[wave] = sqrtf(s);
    } else {
        float s0 = a[0] / fmaxf(norms[wave], NORM_EPS);
        float s1 = a[1] / fmaxf(norms[N_NODES + wave], NORM_EPS);
        float s2 = a[2] / fmaxf(norms[2 * N_NODES + wave], NORM_EPS);
        float s3 = a[3] / fmaxf(sqrtf(s), NORM_EPS);
        if (act) {
            size_t idx = (size_t)wave * HALF_EMB + lane;
            float2 em = ((const float2*)emb)[idx];
            __hip_bfloat162 b1 = xb1[idx];
            __hip_bfloat162 b2 = xb2[idx];
            float2 o;
            o.x = s0 * em.x + s1 * __bfloat162float(b1.x)
                + s2 * __bfloat162float(b2.x) + s3 * ax;
            o.y = s0 * em.y + s1 * __bfloat162float(b1.y)
                + s2 * __bfloat162float(b2.y) + s3 * ay;
            ((float2*)out)[idx] = o;
        }
    }
}

extern "C" void kernel_launch(void* const* d_in, const int* in_sizes, int n_in,
                              void* d_out, int out_size, void* d_ws, size_t ws_size,
                              hipStream_t stream) {
    const int*   adj_row   = (const int*)d_in[0];
    const int*   adj_col   = (const int*)d_in[1];
    const float* adj_val   = (const float*)d_in[2];
    const float* embedding = (const float*)d_in[3];
    const float* a         = (const float*)d_in[4];
    float* out = (float*)d_out;

    // workspace layout. xb2 overlays slab (slab dead after csr_build,
    // xb2 first written in layer-2 spmm — stream-ordered, safe).
    int2* slab   = (int2*)d_ws;                                    // NB*CAP int2 = 12.8 MB
    int2* csr_cv = slab + (size_t)NB * CAP;                        // 800,000 int2
    __hip_bfloat162* xbE = (__hip_bfloat162*)(csr_cv + N_EDGES);   // 10 MB
    __hip_bfloat162* xb1 = xbE + (size_t)N_NODES * HALF_EMB;       // 10 MB
    float* norms = (float*)(xb1 + (size_t)N_NODES * HALF_EMB);     // 3*50,000
    int* row_ptr     = (int*)(norms + 3 * N_NODES);                // 50,001
    int* bucket_cnt  = row_ptr + (N_NODES + 1);                    // NB
    int* bucket_base = bucket_cnt + NB;                            // NB
    __hip_bfloat162* xb2 = (__hip_bfloat162*)slab;                 // overlay

    const int node_blocks = (N_NODES + 3) / 4;          // 4 waves / block
    const int part_blocks = (N_EDGES + EPB - 1) / EPB;  // 782

    // ---- CSR build: partition -> scan -> per-bucket sort ----
    hipMemsetAsync(bucket_cnt, 0, sizeof(int) * NB, stream);
    bucket_scatter<<<part_blocks, 256, 0, stream>>>(adj_row, adj_col, adj_val,
                                                    bucket_cnt, slab);
    scan_buckets<<<1, 1024, 0, stream>>>(bucket_cnt, bucket_base, row_ptr);
    csr_build<<<NB, 256, 0, stream>>>(bucket_cnt, bucket_base, slab, csr_cv, row_ptr);

    // ---- emb prep ----
    conv_emb<<<node_blocks, 256, 0, stream>>>(embedding, norms, xbE);

    // ---- layer 1, 2 (raw bf16 + norm), layer 3 (fused epilogue) ----
    spmm_fused<<<node_blocks, 256, 0, stream>>>(row_ptr, csr_cv, xbE, xb1,
                                                norms + N_NODES, a,
                                                nullptr, nullptr, nullptr, nullptr,
                                                nullptr, 0);
    spmm_fused<<<node_blocks, 256, 0, stream>>>(row_ptr, csr_cv, xb1, xb2,
                                                norms + 2 * N_NODES, a,
                                                nullptr, nullptr, nullptr, nullptr,
                                                nullptr, 0);
    spmm_fused<<<node_blocks, 256, 0, stream>>>(row_ptr, csr_cv, xb2, nullptr,
                                                nullptr, a,
                                                embedding, xb1, xb2, norms,
                                                out, 1);
}

// Round 8
// 247.438 us; speedup vs baseline: 1.1762x; 1.0863x over previous
//
#include <hip/hip_runtime.h>
#include <hip/hip_bf16.h>

#define N_NODES 50000
#define N_EDGES 800000
#define EMB 100
#define HALF_EMB 50
#define NORM_EPS 1e-12f
#define BROWS 64                       // rows per bucket
#define NB ((N_NODES + BROWS - 1) / BROWS)   // 782 buckets
#define CAP 2048                       // slab capacity per bucket (avg fill ~1023)
#define EPB 1024                       // edges per partition block

// Pass 1: block-level radix partition into NB coarse buckets (782 blocks).
// Slab record: ((row<<16)|col, fp32 val bits).
__global__ void bucket_scatter(const int* __restrict__ adj_row,
                               const int* __restrict__ adj_col,
                               const float* __restrict__ adj_val,
                               int* __restrict__ bucket_cnt,
                               int2* __restrict__ slab) {
    __shared__ int hist[NB];
    __shared__ int gbase[NB];
    __shared__ int lcur[NB];
    const int t = threadIdx.x;
    const int base_e = blockIdx.x * EPB;
    for (int i = t; i < NB; i += 256) { hist[i] = 0; lcur[i] = 0; }
    __syncthreads();
    int rows[EPB / 256];
    #pragma unroll
    for (int j = 0; j < EPB / 256; ++j) {
        int e = base_e + j * 256 + t;
        int r = (e < N_EDGES) ? adj_row[e] : -1;
        rows[j] = r;
        if (r >= 0) atomicAdd(&hist[r / BROWS], 1);
    }
    __syncthreads();
    for (int i = t; i < NB; i += 256) {
        int c = hist[i];
        gbase[i] = (c > 0) ? atomicAdd(&bucket_cnt[i], c) : 0;
    }
    __syncthreads();
    #pragma unroll
    for (int j = 0; j < EPB / 256; ++j) {
        int e = base_e + j * 256 + t;
        int r = rows[j];
        if (r >= 0) {
            int b = r / BROWS;
            int p = atomicAdd(&lcur[b], 1);
            unsigned rc = ((unsigned)r << 16) | (unsigned)adj_col[e];
            slab[(size_t)b * CAP + gbase[b] + p] =
                make_int2((int)rc, __float_as_int(adj_val[e]));
        }
    }
}

// Pass 2: per-bucket: compute own global base (prefix over bucket_cnt),
// counting-sort bucket in LDS, emit compressed CSR (col<<16 | bf16(val)) + row_ptr.
__global__ void csr_build(const int* __restrict__ bucket_cnt,
                          const int2* __restrict__ slab,
                          unsigned* __restrict__ csr4,
                          int* __restrict__ row_ptr) {
    __shared__ int2 eds[CAP];
    __shared__ int hist[BROWS];   // later reused as scatter cursor
    __shared__ int incl[BROWS];
    __shared__ int red[256];
    const int b = blockIdx.x, t = threadIdx.x;
    // --- embedded exclusive prefix: base = sum_{i<b} cnt[i] ---
    int part = 0;
    for (int i = t; i < b; i += 256) part += bucket_cnt[i];
    red[t] = part;
    __syncthreads();
    #pragma unroll
    for (int off = 128; off > 0; off >>= 1) {
        if (t < off) red[t] += red[t + off];
        __syncthreads();
    }
    const int base = red[0];
    const int cnt = bucket_cnt[b];
    for (int i = t; i < cnt; i += 256) eds[i] = slab[(size_t)b * CAP + i];
    if (t < BROWS) hist[t] = 0;
    __syncthreads();
    for (int i = t; i < cnt; i += 256)
        atomicAdd(&hist[(int)(((unsigned)eds[i].x) >> 16) & (BROWS - 1)], 1);
    __syncthreads();
    int v = (t < BROWS) ? hist[t] : 0;
    if (t < BROWS) incl[t] = v;
    __syncthreads();
    #pragma unroll
    for (int off = 1; off < BROWS; off <<= 1) {
        int n = (t >= off && t < BROWS) ? incl[t - off] : 0;
        __syncthreads();
        if (t < BROWS) incl[t] += n;
        __syncthreads();
    }
    int ex = (t < BROWS) ? (incl[t] - v) : 0;
    __syncthreads();
    if (t < BROWS) hist[t] = ex;          // cursor init
    int gr = b * BROWS + t;
    if (t < BROWS && gr < N_NODES) row_ptr[gr] = base + ex;
    if (b == 0 && t == 0) row_ptr[N_NODES] = N_EDGES;
    __syncthreads();
    for (int i = t; i < cnt; i += 256) {
        int2 e = eds[i];
        int l = (int)(((unsigned)e.x) >> 16) & (BROWS - 1);
        int p = atomicAdd(&hist[l], 1);
        unsigned col = (unsigned)e.x & 0xFFFFu;
        __hip_bfloat16 hv = __float2bfloat16(__int_as_float(e.y));
        unsigned vb = (unsigned)*reinterpret_cast<unsigned short*>(&hv);
        csr4[base + p] = (col << 16) | vb;
    }
}

// Emb prep: xbE = bf16(emb), norms[0][node] = ||emb_row||.
__global__ void conv_emb(const float* __restrict__ emb, float* __restrict__ norm0,
                         __hip_bfloat162* __restrict__ xb) {
    int wave = blockIdx.x * (blockDim.x >> 6) + (threadIdx.x >> 6);
    int lane = threadIdx.x & 63;
    if (wave >= N_NODES) return;
    float2 v = make_float2(0.0f, 0.0f);
    size_t idx = (size_t)wave * HALF_EMB + lane;
    if (lane < HALF_EMB) v = ((const float2*)emb)[idx];
    float s = v.x * v.x + v.y * v.y;
    #pragma unroll
    for (int off = 32; off > 0; off >>= 1) s += __shfl_xor(s, off);
    if (lane == 0) norm0[wave] = sqrtf(s);
    if (lane < HALF_EMB) {
        __hip_bfloat162 b;
        b.x = __float2bfloat16(v.x);
        b.y = __float2bfloat16(v.y);
        xb[idx] = b;
    }
}

// SpMM: lane-coalesced edge fetch + shfl broadcast, bf16 gather, fp32 accumulate.
// rec = col<<16 | bf16(val): col = rec>>16, val = bits(rec<<16) as f32 (exact).
// Non-final: write bf16 y + per-node norm. Final: full weighted-sum epilogue.
__global__ void spmm_fused(const int* __restrict__ row_ptr,
                           const unsigned* __restrict__ csr4,
                           const __hip_bfloat162* __restrict__ xb,
                           __hip_bfloat162* __restrict__ yb,
                           float* __restrict__ norm_out,
                           const float* __restrict__ a,
                           const __hip_bfloat162* __restrict__ ep0,
                           const __hip_bfloat162* __restrict__ ep1,
                           const float* __restrict__ norms,
                           float* __restrict__ out,
                           int final_layer) {
    int wave = blockIdx.x * (blockDim.x >> 6) + (threadIdx.x >> 6);
    int lane = threadIdx.x & 63;
    if (wave >= N_NODES) return;
    int start = row_ptr[wave];
    int end   = row_ptr[wave + 1];
    int deg   = end - start;
    // one coalesced 4B load fetches the whole edge list (deg <= 64 in practice)
    unsigned myrec = (lane < deg) ? csr4[start + lane] : 0u;
    bool act = (lane < HALF_EMB);
    float ax = 0.0f, ay = 0.0f;
    int dn = (deg < 64) ? deg : 64;
    int d = 0;
    for (; d + 3 < dn; d += 4) {
        unsigned r0 = __shfl(myrec, d);
        unsigned r1 = __shfl(myrec, d + 1);
        unsigned r2 = __shfl(myrec, d + 2);
        unsigned r3 = __shfl(myrec, d + 3);
        if (act) {
            __hip_bfloat162 p0 = xb[(size_t)(r0 >> 16) * HALF_EMB + lane];
            __hip_bfloat162 p1 = xb[(size_t)(r1 >> 16) * HALF_EMB + lane];
            __hip_bfloat162 p2 = xb[(size_t)(r2 >> 16) * HALF_EMB + lane];
            __hip_bfloat162 p3 = xb[(size_t)(r3 >> 16) * HALF_EMB + lane];
            float v0 = __uint_as_float(r0 << 16);
            float v1 = __uint_as_float(r1 << 16);
            float v2 = __uint_as_float(r2 << 16);
            float v3 = __uint_as_float(r3 << 16);
            ax += v0 * __bfloat162float(p0.x); ay += v0 * __bfloat162float(p0.y);
            ax += v1 * __bfloat162float(p1.x); ay += v1 * __bfloat162float(p1.y);
            ax += v2 * __bfloat162float(p2.x); ay += v2 * __bfloat162float(p2.y);
            ax += v3 * __bfloat162float(p3.x); ay += v3 * __bfloat162float(p3.y);
        }
    }
    for (; d < dn; ++d) {
        unsigned r = __shfl(myrec, d);
        if (act) {
            __hip_bfloat162 p = xb[(size_t)(r >> 16) * HALF_EMB + lane];
            float v = __uint_as_float(r << 16);
            ax += v * __bfloat162float(p.x);
            ay += v * __bfloat162float(p.y);
        }
    }
    // overflow fallback (deg > 64): essentially never taken for this input
    for (int e = start + 64; e < end; ++e) {
        unsigned r = csr4[e];
        if (act) {
            __hip_bfloat162 p = xb[(size_t)(r >> 16) * HALF_EMB + lane];
            float v = __uint_as_float(r << 16);
            ax += v * __bfloat162float(p.x);
            ay += v * __bfloat162float(p.y);
        }
    }
    float s = ax * ax + ay * ay;
    #pragma unroll
    for (int off = 32; off > 0; off >>= 1) s += __shfl_xor(s, off);
    if (!final_layer) {
        if (act) {
            size_t idx = (size_t)wave * HALF_EMB + lane;
            __hip_bfloat162 bb;
            bb.x = __float2bfloat16(ax);
            bb.y = __float2bfloat16(ay);
            yb[idx] = bb;
        }
        if (lane == 0) norm_out[wave] = sqrtf(s);
    } else {
        float s0 = a[0] / fmaxf(norms[wave], NORM_EPS);
        float s1 = a[1] / fmaxf(norms[N_NODES + wave], NORM_EPS);
        float s2 = a[2] / fmaxf(norms[2 * N_NODES + wave], NORM_EPS);
        float s3 = a[3] / fmaxf(sqrtf(s), NORM_EPS);
        if (act) {
            size_t idx = (size_t)wave * HALF_EMB + lane;
            __hip_bfloat162 e0 = ep0[idx];   // bf16(emb)
            __hip_bfloat162 e1 = ep1[idx];   // x1
            __hip_bfloat162 e2 = xb[idx];    // x2 (the gather table, L2-warm)
            float2 o;
            o.x = s0 * __bfloat162float(e0.x) + s1 * __bfloat162float(e1.x)
                + s2 * __bfloat162float(e2.x) + s3 * ax;
            o.y = s0 * __bfloat162float(e0.y) + s1 * __bfloat162float(e1.y)
                + s2 * __bfloat162float(e2.y) + s3 * ay;
            ((float2*)out)[idx] = o;
        }
    }
}

extern "C" void kernel_launch(void* const* d_in, const int* in_sizes, int n_in,
                              void* d_out, int out_size, void* d_ws, size_t ws_size,
                              hipStream_t stream) {
    const int*   adj_row   = (const int*)d_in[0];
    const int*   adj_col   = (const int*)d_in[1];
    const float* adj_val   = (const float*)d_in[2];
    const float* embedding = (const float*)d_in[3];
    const float* a         = (const float*)d_in[4];
    float* out = (float*)d_out;

    // workspace layout. xb2 overlays slab (slab dead after csr_build,
    // xb2 first written in layer-2 spmm — stream-ordered, safe).
    int2* slab     = (int2*)d_ws;                                  // 12.8 MB
    unsigned* csr4 = (unsigned*)(slab + (size_t)NB * CAP);         // 3.2 MB
    __hip_bfloat162* xbE = (__hip_bfloat162*)(csr4 + N_EDGES);     // 10 MB
    __hip_bfloat162* xb1 = xbE + (size_t)N_NODES * HALF_EMB;       // 10 MB
    float* norms = (float*)(xb1 + (size_t)N_NODES * HALF_EMB);     // 3*50,000
    int* row_ptr    = (int*)(norms + 3 * N_NODES);                 // 50,001
    int* bucket_cnt = row_ptr + (N_NODES + 1);                     // NB
    __hip_bfloat162* xb2 = (__hip_bfloat162*)slab;                 // overlay

    const int node_blocks = (N_NODES + 3) / 4;          // 4 waves / block
    const int part_blocks = (N_EDGES + EPB - 1) / EPB;  // 782

    // ---- CSR build: partition -> per-bucket sort (scan fused in) ----
    hipMemsetAsync(bucket_cnt, 0, sizeof(int) * NB, stream);
    bucket_scatter<<<part_blocks, 256, 0, stream>>>(adj_row, adj_col, adj_val,
                                                    bucket_cnt, slab);
    csr_build<<<NB, 256, 0, stream>>>(bucket_cnt, slab, csr4, row_ptr);

    // ---- emb prep ----
    conv_emb<<<node_blocks, 256, 0, stream>>>(embedding, norms, xbE);

    // ---- layer 1, 2 (raw bf16 + norm), layer 3 (fused epilogue) ----
    spmm_fused<<<node_blocks, 256, 0, stream>>>(row_ptr, csr4, xbE, xb1,
                                                norms + N_NODES, a,
                                                nullptr, nullptr, nullptr,
                                                nullptr, 0);
    spmm_fused<<<node_blocks, 256, 0, stream>>>(row_ptr, csr4, xb1, xb2,
                                                norms + 2 * N_NODES, a,
                                                nullptr, nullptr, nullptr,
                                                nullptr, 0);
    spmm_fused<<<node_blocks, 256, 0, stream>>>(row_ptr, csr4, xb2, nullptr,
                                                nullptr, a,
                                                xbE, xb1, norms,
                                                out, 1);
}

// Round 9
// 225.236 us; speedup vs baseline: 1.2922x; 1.0986x over previous
//
#include <hip/hip_runtime.h>
#include <hip/hip_bf16.h>

#define N_NODES 50000
#define N_EDGES 800000
#define EMB 100
#define HALF_EMB 50
#define NORM_EPS 1e-12f
#define BROWS 128                      // rows per bucket
#define NB ((N_NODES + BROWS - 1) / BROWS)   // 391 buckets
#define CAP 4096                       // slab capacity per bucket (avg fill ~2046)
#define EPB 4096                       // edges per partition block -> run len ~10.5

#define CONV_BLOCKS ((N_NODES + 3) / 4)      // 12500 (4 waves/block)

// Pass 1: block-level radix partition into NB coarse buckets (196 blocks).
// Slab record: ((row<<16)|col, fp32 val bits).
__global__ void bucket_scatter(const int* __restrict__ adj_row,
                               const int* __restrict__ adj_col,
                               const float* __restrict__ adj_val,
                               int* __restrict__ bucket_cnt,
                               int2* __restrict__ slab) {
    __shared__ int hist[NB];
    __shared__ int cur[NB];     // becomes write cursor (= reserved global base)
    const int t = threadIdx.x;
    const int base_e = blockIdx.x * EPB;
    for (int i = t; i < NB; i += 256) hist[i] = 0;
    __syncthreads();
    int rows[EPB / 256];
    #pragma unroll
    for (int j = 0; j < EPB / 256; ++j) {
        int e = base_e + j * 256 + t;
        int r = (e < N_EDGES) ? adj_row[e] : -1;
        rows[j] = r;
        if (r >= 0) atomicAdd(&hist[r >> 7], 1);
    }
    __syncthreads();
    for (int i = t; i < NB; i += 256) {
        int c = hist[i];
        cur[i] = (c > 0) ? atomicAdd(&bucket_cnt[i], c) : 0;
    }
    __syncthreads();
    #pragma unroll
    for (int j = 0; j < EPB / 256; ++j) {
        int e = base_e + j * 256 + t;
        int r = rows[j];
        if (r >= 0) {
            int b = r >> 7;
            int p = atomicAdd(&cur[b], 1);
            unsigned rc = ((unsigned)r << 16) | (unsigned)adj_col[e];
            slab[(size_t)b * CAP + p] = make_int2((int)rc, __float_as_int(adj_val[e]));
        }
    }
}

// Pass 2 (merged dispatch):
//   blocks [0, NB)            : per-bucket counting sort -> compressed CSR + row_ptr
//   blocks [NB, NB+CONV_BLOCKS): conv_emb (bf16 cast + row norms of embedding)
__global__ void csr_build_conv(const int* __restrict__ bucket_cnt,
                               const int2* __restrict__ slab,
                               unsigned* __restrict__ csr4,
                               int* __restrict__ row_ptr,
                               const float* __restrict__ emb,
                               float* __restrict__ norm0,
                               __hip_bfloat162* __restrict__ xb) {
    __shared__ int2 eds[CAP];
    __shared__ int hist[BROWS];   // later reused as scatter cursor
    __shared__ int incl[BROWS];
    __shared__ int red[256];
    const int t = threadIdx.x;
    if (blockIdx.x >= NB) {
        // ---- conv_emb part ----
        int wave = (blockIdx.x - NB) * 4 + (t >> 6);
        int lane = t & 63;
        if (wave >= N_NODES) return;
        float2 v = make_float2(0.0f, 0.0f);
        size_t idx = (size_t)wave * HALF_EMB + lane;
        if (lane < HALF_EMB) v = ((const float2*)emb)[idx];
        float s = v.x * v.x + v.y * v.y;
        #pragma unroll
        for (int off = 32; off > 0; off >>= 1) s += __shfl_xor(s, off);
        if (lane == 0) norm0[wave] = sqrtf(s);
        if (lane < HALF_EMB) {
            __hip_bfloat162 b;
            b.x = __float2bfloat16(v.x);
            b.y = __float2bfloat16(v.y);
            xb[idx] = b;
        }
        return;
    }
    // ---- csr_build part ----
    const int b = blockIdx.x;
    // embedded exclusive prefix: base = sum_{i<b} cnt[i]
    int part = 0;
    for (int i = t; i < b; i += 256) part += bucket_cnt[i];
    red[t] = part;
    __syncthreads();
    #pragma unroll
    for (int off = 128; off > 0; off >>= 1) {
        if (t < off) red[t] += red[t + off];
        __syncthreads();
    }
    const int base = red[0];
    const int cnt = bucket_cnt[b];
    for (int i = t; i < cnt; i += 256) eds[i] = slab[(size_t)b * CAP + i];
    if (t < BROWS) hist[t] = 0;
    __syncthreads();
    for (int i = t; i < cnt; i += 256)
        atomicAdd(&hist[(int)(((unsigned)eds[i].x) >> 16) & (BROWS - 1)], 1);
    __syncthreads();
    int v = (t < BROWS) ? hist[t] : 0;
    if (t < BROWS) incl[t] = v;
    __syncthreads();
    #pragma unroll
    for (int off = 1; off < BROWS; off <<= 1) {
        int n = (t >= off && t < BROWS) ? incl[t - off] : 0;
        __syncthreads();
        if (t < BROWS) incl[t] += n;
        __syncthreads();
    }
    int ex = (t < BROWS) ? (incl[t] - v) : 0;
    __syncthreads();
    if (t < BROWS) hist[t] = ex;          // cursor init
    int gr = b * BROWS + t;
    if (t < BROWS && gr < N_NODES) row_ptr[gr] = base + ex;
    if (b == 0 && t == 0) row_ptr[N_NODES] = N_EDGES;
    __syncthreads();
    for (int i = t; i < cnt; i += 256) {
        int2 e = eds[i];
        int l = (int)(((unsigned)e.x) >> 16) & (BROWS - 1);
        int p = atomicAdd(&hist[l], 1);
        unsigned col = (unsigned)e.x & 0xFFFFu;
        __hip_bfloat16 hv = __float2bfloat16(__int_as_float(e.y));
        unsigned vb = (unsigned)*reinterpret_cast<unsigned short*>(&hv);
        csr4[base + p] = (col << 16) | vb;
    }
}

// SpMM: lane-coalesced edge fetch + shfl broadcast, bf16 gather, fp32 accumulate.
// rec = col<<16 | bf16(val): col = rec>>16, val = bits(rec<<16) as f32 (exact).
// Non-final: write bf16 y + per-node norm. Final: full weighted-sum epilogue.
__global__ void spmm_fused(const int* __restrict__ row_ptr,
                           const unsigned* __restrict__ csr4,
                           const __hip_bfloat162* __restrict__ xb,
                           __hip_bfloat162* __restrict__ yb,
                           float* __restrict__ norm_out,
                           const float* __restrict__ a,
                           const __hip_bfloat162* __restrict__ ep0,
                           const __hip_bfloat162* __restrict__ ep1,
                           const float* __restrict__ norms,
                           float* __restrict__ out,
                           int final_layer) {
    int wave = blockIdx.x * (blockDim.x >> 6) + (threadIdx.x >> 6);
    int lane = threadIdx.x & 63;
    if (wave >= N_NODES) return;
    int start = row_ptr[wave];
    int end   = row_ptr[wave + 1];
    int deg   = end - start;
    // one coalesced 4B load fetches the whole edge list (deg <= 64 in practice)
    unsigned myrec = (lane < deg) ? csr4[start + lane] : 0u;
    bool act = (lane < HALF_EMB);
    float ax = 0.0f, ay = 0.0f;
    int dn = (deg < 64) ? deg : 64;
    int d = 0;
    for (; d + 3 < dn; d += 4) {
        unsigned r0 = __shfl(myrec, d);
        unsigned r1 = __shfl(myrec, d + 1);
        unsigned r2 = __shfl(myrec, d + 2);
        unsigned r3 = __shfl(myrec, d + 3);
        if (act) {
            __hip_bfloat162 p0 = xb[(size_t)(r0 >> 16) * HALF_EMB + lane];
            __hip_bfloat162 p1 = xb[(size_t)(r1 >> 16) * HALF_EMB + lane];
            __hip_bfloat162 p2 = xb[(size_t)(r2 >> 16) * HALF_EMB + lane];
            __hip_bfloat162 p3 = xb[(size_t)(r3 >> 16) * HALF_EMB + lane];
            float v0 = __uint_as_float(r0 << 16);
            float v1 = __uint_as_float(r1 << 16);
            float v2 = __uint_as_float(r2 << 16);
            float v3 = __uint_as_float(r3 << 16);
            ax += v0 * __bfloat162float(p0.x); ay += v0 * __bfloat162float(p0.y);
            ax += v1 * __bfloat162float(p1.x); ay += v1 * __bfloat162float(p1.y);
            ax += v2 * __bfloat162float(p2.x); ay += v2 * __bfloat162float(p2.y);
            ax += v3 * __bfloat162float(p3.x); ay += v3 * __bfloat162float(p3.y);
        }
    }
    for (; d < dn; ++d) {
        unsigned r = __shfl(myrec, d);
        if (act) {
            __hip_bfloat162 p = xb[(size_t)(r >> 16) * HALF_EMB + lane];
            float v = __uint_as_float(r << 16);
            ax += v * __bfloat162float(p.x);
            ay += v * __bfloat162float(p.y);
        }
    }
    // overflow fallback (deg > 64): essentially never taken for this input
    for (int e = start + 64; e < end; ++e) {
        unsigned r = csr4[e];
        if (act) {
            __hip_bfloat162 p = xb[(size_t)(r >> 16) * HALF_EMB + lane];
            float v = __uint_as_float(r << 16);
            ax += v * __bfloat162float(p.x);
            ay += v * __bfloat162float(p.y);
        }
    }
    float s = ax * ax + ay * ay;
    #pragma unroll
    for (int off = 32; off > 0; off >>= 1) s += __shfl_xor(s, off);
    if (!final_layer) {
        if (act) {
            size_t idx = (size_t)wave * HALF_EMB + lane;
            __hip_bfloat162 bb;
            bb.x = __float2bfloat16(ax);
            bb.y = __float2bfloat16(ay);
            yb[idx] = bb;
        }
        if (lane == 0) norm_out[wave] = sqrtf(s);
    } else {
        float s0 = a[0] / fmaxf(norms[wave], NORM_EPS);
        float s1 = a[1] / fmaxf(norms[N_NODES + wave], NORM_EPS);
        float s2 = a[2] / fmaxf(norms[2 * N_NODES + wave], NORM_EPS);
        float s3 = a[3] / fmaxf(sqrtf(s), NORM_EPS);
        if (act) {
            size_t idx = (size_t)wave * HALF_EMB + lane;
            __hip_bfloat162 e0 = ep0[idx];   // bf16(emb)
            __hip_bfloat162 e1 = ep1[idx];   // x1
            __hip_bfloat162 e2 = xb[idx];    // x2 (the gather table, L2-warm)
            float2 o;
            o.x = s0 * __bfloat162float(e0.x) + s1 * __bfloat162float(e1.x)
                + s2 * __bfloat162float(e2.x) + s3 * ax;
            o.y = s0 * __bfloat162float(e0.y) + s1 * __bfloat162float(e1.y)
                + s2 * __bfloat162float(e2.y) + s3 * ay;
            ((float2*)out)[idx] = o;
        }
    }
}

extern "C" void kernel_launch(void* const* d_in, const int* in_sizes, int n_in,
                              void* d_out, int out_size, void* d_ws, size_t ws_size,
                              hipStream_t stream) {
    const int*   adj_row   = (const int*)d_in[0];
    const int*   adj_col   = (const int*)d_in[1];
    const float* adj_val   = (const float*)d_in[2];
    const float* embedding = (const float*)d_in[3];
    const float* a         = (const float*)d_in[4];
    float* out = (float*)d_out;

    // workspace layout. xb2 overlays slab (slab dead after csr_build_conv,
    // xb2 first written in layer-2 spmm — stream-ordered, safe).
    int2* slab     = (int2*)d_ws;                                  // 12.8 MB
    unsigned* csr4 = (unsigned*)(slab + (size_t)NB * CAP);         // 3.2 MB
    __hip_bfloat162* xbE = (__hip_bfloat162*)(csr4 + N_EDGES);     // 10 MB
    __hip_bfloat162* xb1 = xbE + (size_t)N_NODES * HALF_EMB;       // 10 MB
    float* norms = (float*)(xb1 + (size_t)N_NODES * HALF_EMB);     // 3*50,000
    int* row_ptr    = (int*)(norms + 3 * N_NODES);                 // 50,001
    int* bucket_cnt = row_ptr + (N_NODES + 1);                     // NB
    __hip_bfloat162* xb2 = (__hip_bfloat162*)slab;                 // overlay

    const int node_blocks = (N_NODES + 3) / 4;          // 4 waves / block
    const int part_blocks = (N_EDGES + EPB - 1) / EPB;  // 196

    // ---- CSR build: partition -> (per-bucket sort + emb prep, one dispatch) ----
    hipMemsetAsync(bucket_cnt, 0, sizeof(int) * NB, stream);
    bucket_scatter<<<part_blocks, 256, 0, stream>>>(adj_row, adj_col, adj_val,
                                                    bucket_cnt, slab);
    csr_build_conv<<<NB + CONV_BLOCKS, 256, 0, stream>>>(bucket_cnt, slab, csr4,
                                                         row_ptr, embedding,
                                                         norms, xbE);

    // ---- layer 1, 2 (raw bf16 + norm), layer 3 (fused epilogue) ----
    spmm_fused<<<node_blocks, 256, 0, stream>>>(row_ptr, csr4, xbE, xb1,
                                                norms + N_NODES, a,
                                                nullptr, nullptr, nullptr,
                                                nullptr, 0);
    spmm_fused<<<node_blocks, 256, 0, stream>>>(row_ptr, csr4, xb1, xb2,
                                                norms + 2 * N_NODES, a,
                                                nullptr, nullptr, nullptr,
                                                nullptr, 0);
    spmm_fused<<<node_blocks, 256, 0, stream>>>(row_ptr, csr4, xb2, nullptr,
                                                nullptr, a,
                                                xbE, xb1, norms,
                                                out, 1);
}

// Round 10
// 224.688 us; speedup vs baseline: 1.2953x; 1.0024x over previous
//
#include <hip/hip_runtime.h>
#include <hip/hip_bf16.h>

#define N_NODES 50000
#define N_EDGES 800000
#define EMB 100
#define HALF_EMB 50
#define NORM_EPS 1e-12f
#define BROWS 128                      // rows per bucket
#define NB ((N_NODES + BROWS - 1) / BROWS)   // 391 buckets
#define CAP 4096                       // slab capacity per bucket (avg fill ~2046)
#define EPB 4096                       // edges per partition block -> run len ~10.5

#define CONV_BLOCKS ((N_NODES + 3) / 4)      // 12500 (4 waves/block)

// Pass 1: block-level radix partition into NB coarse buckets (196 blocks).
// Slab record: ((row<<16)|col, fp32 val bits).
__global__ void bucket_scatter(const int* __restrict__ adj_row,
                               const int* __restrict__ adj_col,
                               const float* __restrict__ adj_val,
                               int* __restrict__ bucket_cnt,
                               int2* __restrict__ slab) {
    __shared__ int hist[NB];
    __shared__ int cur[NB];     // becomes write cursor (= reserved global base)
    const int t = threadIdx.x;
    const int base_e = blockIdx.x * EPB;
    for (int i = t; i < NB; i += 256) hist[i] = 0;
    __syncthreads();
    int rows[EPB / 256];
    #pragma unroll
    for (int j = 0; j < EPB / 256; ++j) {
        int e = base_e + j * 256 + t;
        int r = (e < N_EDGES) ? adj_row[e] : -1;
        rows[j] = r;
        if (r >= 0) atomicAdd(&hist[r >> 7], 1);
    }
    __syncthreads();
    for (int i = t; i < NB; i += 256) {
        int c = hist[i];
        cur[i] = (c > 0) ? atomicAdd(&bucket_cnt[i], c) : 0;
    }
    __syncthreads();
    #pragma unroll
    for (int j = 0; j < EPB / 256; ++j) {
        int e = base_e + j * 256 + t;
        int r = rows[j];
        if (r >= 0) {
            int b = r >> 7;
            int p = atomicAdd(&cur[b], 1);
            unsigned rc = ((unsigned)r << 16) | (unsigned)adj_col[e];
            slab[(size_t)b * CAP + p] = make_int2((int)rc, __float_as_int(adj_val[e]));
        }
    }
}

// Pass 2 (merged dispatch):
//   blocks [0, NB)            : per-bucket counting sort -> compressed CSR + row_ptr
//   blocks [NB, NB+CONV_BLOCKS): conv_emb (bf16 cast + row norms of embedding)
__global__ void csr_build_conv(const int* __restrict__ bucket_cnt,
                               const int2* __restrict__ slab,
                               unsigned* __restrict__ csr4,
                               int* __restrict__ row_ptr,
                               const float* __restrict__ emb,
                               float* __restrict__ norm0,
                               __hip_bfloat162* __restrict__ xb) {
    __shared__ int2 eds[CAP];
    __shared__ int hist[BROWS];   // later reused as scatter cursor
    __shared__ int incl[BROWS];
    __shared__ int red[256];
    const int t = threadIdx.x;
    if (blockIdx.x >= NB) {
        // ---- conv_emb part ----
        int wave = (blockIdx.x - NB) * 4 + (t >> 6);
        int lane = t & 63;
        if (wave >= N_NODES) return;
        float2 v = make_float2(0.0f, 0.0f);
        size_t idx = (size_t)wave * HALF_EMB + lane;
        if (lane < HALF_EMB) v = ((const float2*)emb)[idx];
        float s = v.x * v.x + v.y * v.y;
        #pragma unroll
        for (int off = 32; off > 0; off >>= 1) s += __shfl_xor(s, off);
        if (lane == 0) norm0[wave] = sqrtf(s);
        if (lane < HALF_EMB) {
            __hip_bfloat162 b;
            b.x = __float2bfloat16(v.x);
            b.y = __float2bfloat16(v.y);
            xb[idx] = b;
        }
        return;
    }
    // ---- csr_build part ----
    const int b = blockIdx.x;
    // embedded exclusive prefix: base = sum_{i<b} cnt[i]
    int part = 0;
    for (int i = t; i < b; i += 256) part += bucket_cnt[i];
    red[t] = part;
    __syncthreads();
    #pragma unroll
    for (int off = 128; off > 0; off >>= 1) {
        if (t < off) red[t] += red[t + off];
        __syncthreads();
    }
    const int base = red[0];
    const int cnt = bucket_cnt[b];
    for (int i = t; i < cnt; i += 256) eds[i] = slab[(size_t)b * CAP + i];
    if (t < BROWS) hist[t] = 0;
    __syncthreads();
    for (int i = t; i < cnt; i += 256)
        atomicAdd(&hist[(int)(((unsigned)eds[i].x) >> 16) & (BROWS - 1)], 1);
    __syncthreads();
    int v = (t < BROWS) ? hist[t] : 0;
    if (t < BROWS) incl[t] = v;
    __syncthreads();
    #pragma unroll
    for (int off = 1; off < BROWS; off <<= 1) {
        int n = (t >= off && t < BROWS) ? incl[t - off] : 0;
        __syncthreads();
        if (t < BROWS) incl[t] += n;
        __syncthreads();
    }
    int ex = (t < BROWS) ? (incl[t] - v) : 0;
    __syncthreads();
    if (t < BROWS) hist[t] = ex;          // cursor init
    int gr = b * BROWS + t;
    if (t < BROWS && gr < N_NODES) row_ptr[gr] = base + ex;
    if (b == 0 && t == 0) row_ptr[N_NODES] = N_EDGES;
    __syncthreads();
    for (int i = t; i < cnt; i += 256) {
        int2 e = eds[i];
        int l = (int)(((unsigned)e.x) >> 16) & (BROWS - 1);
        int p = atomicAdd(&hist[l], 1);
        unsigned col = (unsigned)e.x & 0xFFFFu;
        __hip_bfloat16 hv = __float2bfloat16(__int_as_float(e.y));
        unsigned vb = (unsigned)*reinterpret_cast<unsigned short*>(&hv);
        csr4[base + p] = (col << 16) | vb;
    }
}

// SpMM: lane-coalesced edge fetch + shfl broadcast, bf16 gather (raw uint),
// float2 accumulate (pk_fma-friendly), unroll 8 for memory-level parallelism.
// rec = col<<16 | bf16(val): col = rec>>16, val = bits(rec<<16) as f32 (exact).
// xb rows viewed as uint: u<<16 -> even feature, u&0xFFFF0000 -> odd feature.
__global__ void spmm_fused(const int* __restrict__ row_ptr,
                           const unsigned* __restrict__ csr4,
                           const unsigned* __restrict__ xb,
                           __hip_bfloat162* __restrict__ yb,
                           float* __restrict__ norm_out,
                           const float* __restrict__ a,
                           const __hip_bfloat162* __restrict__ ep0,
                           const __hip_bfloat162* __restrict__ ep1,
                           const float* __restrict__ norms,
                           float* __restrict__ out,
                           int final_layer) {
    int wave = blockIdx.x * (blockDim.x >> 6) + (threadIdx.x >> 6);
    int lane = threadIdx.x & 63;
    if (wave >= N_NODES) return;
    int start = row_ptr[wave];
    int end   = row_ptr[wave + 1];
    int deg   = end - start;
    // one coalesced 4B load fetches the whole edge list (deg <= 64 in practice)
    unsigned myrec = (lane < deg) ? csr4[start + lane] : 0u;
    bool act = (lane < HALF_EMB);
    float2 acc = make_float2(0.0f, 0.0f);
    int dn = (deg < 64) ? deg : 64;
    int d = 0;
    for (; d + 7 < dn; d += 8) {
        unsigned r0 = __shfl(myrec, d);
        unsigned r1 = __shfl(myrec, d + 1);
        unsigned r2 = __shfl(myrec, d + 2);
        unsigned r3 = __shfl(myrec, d + 3);
        unsigned r4 = __shfl(myrec, d + 4);
        unsigned r5 = __shfl(myrec, d + 5);
        unsigned r6 = __shfl(myrec, d + 6);
        unsigned r7 = __shfl(myrec, d + 7);
        if (act) {
            unsigned u0 = xb[(size_t)(r0 >> 16) * HALF_EMB + lane];
            unsigned u1 = xb[(size_t)(r1 >> 16) * HALF_EMB + lane];
            unsigned u2 = xb[(size_t)(r2 >> 16) * HALF_EMB + lane];
            unsigned u3 = xb[(size_t)(r3 >> 16) * HALF_EMB + lane];
            unsigned u4 = xb[(size_t)(r4 >> 16) * HALF_EMB + lane];
            unsigned u5 = xb[(size_t)(r5 >> 16) * HALF_EMB + lane];
            unsigned u6 = xb[(size_t)(r6 >> 16) * HALF_EMB + lane];
            unsigned u7 = xb[(size_t)(r7 >> 16) * HALF_EMB + lane];
            float v0 = __uint_as_float(r0 << 16);
            float v1 = __uint_as_float(r1 << 16);
            float v2 = __uint_as_float(r2 << 16);
            float v3 = __uint_as_float(r3 << 16);
            float v4 = __uint_as_float(r4 << 16);
            float v5 = __uint_as_float(r5 << 16);
            float v6 = __uint_as_float(r6 << 16);
            float v7 = __uint_as_float(r7 << 16);
            acc.x += v0 * __uint_as_float(u0 << 16);
            acc.y += v0 * __uint_as_float(u0 & 0xFFFF0000u);
            acc.x += v1 * __uint_as_float(u1 << 16);
            acc.y += v1 * __uint_as_float(u1 & 0xFFFF0000u);
            acc.x += v2 * __uint_as_float(u2 << 16);
            acc.y += v2 * __uint_as_float(u2 & 0xFFFF0000u);
            acc.x += v3 * __uint_as_float(u3 << 16);
            acc.y += v3 * __uint_as_float(u3 & 0xFFFF0000u);
            acc.x += v4 * __uint_as_float(u4 << 16);
            acc.y += v4 * __uint_as_float(u4 & 0xFFFF0000u);
            acc.x += v5 * __uint_as_float(u5 << 16);
            acc.y += v5 * __uint_as_float(u5 & 0xFFFF0000u);
            acc.x += v6 * __uint_as_float(u6 << 16);
            acc.y += v6 * __uint_as_float(u6 & 0xFFFF0000u);
            acc.x += v7 * __uint_as_float(u7 << 16);
            acc.y += v7 * __uint_as_float(u7 & 0xFFFF0000u);
        }
    }
    for (; d < dn; ++d) {
        unsigned r = __shfl(myrec, d);
        if (act) {
            unsigned u = xb[(size_t)(r >> 16) * HALF_EMB + lane];
            float v = __uint_as_float(r << 16);
            acc.x += v * __uint_as_float(u << 16);
            acc.y += v * __uint_as_float(u & 0xFFFF0000u);
        }
    }
    // overflow fallback (deg > 64): essentially never taken for this input
    for (int e = start + 64; e < end; ++e) {
        unsigned r = csr4[e];
        if (act) {
            unsigned u = xb[(size_t)(r >> 16) * HALF_EMB + lane];
            float v = __uint_as_float(r << 16);
            acc.x += v * __uint_as_float(u << 16);
            acc.y += v * __uint_as_float(u & 0xFFFF0000u);
        }
    }
    float s = acc.x * acc.x + acc.y * acc.y;
    #pragma unroll
    for (int off = 32; off > 0; off >>= 1) s += __shfl_xor(s, off);
    if (!final_layer) {
        if (act) {
            size_t idx = (size_t)wave * HALF_EMB + lane;
            __hip_bfloat162 bb;
            bb.x = __float2bfloat16(acc.x);
            bb.y = __float2bfloat16(acc.y);
            yb[idx] = bb;
        }
        if (lane == 0) norm_out[wave] = sqrtf(s);
    } else {
        float s0 = a[0] / fmaxf(norms[wave], NORM_EPS);
        float s1 = a[1] / fmaxf(norms[N_NODES + wave], NORM_EPS);
        float s2 = a[2] / fmaxf(norms[2 * N_NODES + wave], NORM_EPS);
        float s3 = a[3] / fmaxf(sqrtf(s), NORM_EPS);
        if (act) {
            size_t idx = (size_t)wave * HALF_EMB + lane;
            __hip_bfloat162 e0 = ep0[idx];   // bf16(emb)
            __hip_bfloat162 e1 = ep1[idx];   // x1
            unsigned u2 = xb[idx];           // x2 (the gather table, L2-warm)
            float2 o;
            o.x = s0 * __bfloat162float(e0.x) + s1 * __bfloat162float(e1.x)
                + s2 * __uint_as_float(u2 << 16) + s3 * acc.x;
            o.y = s0 * __bfloat162float(e0.y) + s1 * __bfloat162float(e1.y)
                + s2 * __uint_as_float(u2 & 0xFFFF0000u) + s3 * acc.y;
            ((float2*)out)[idx] = o;
        }
    }
}

extern "C" void kernel_launch(void* const* d_in, const int* in_sizes, int n_in,
                              void* d_out, int out_size, void* d_ws, size_t ws_size,
                              hipStream_t stream) {
    const int*   adj_row   = (const int*)d_in[0];
    const int*   adj_col   = (const int*)d_in[1];
    const float* adj_val   = (const float*)d_in[2];
    const float* embedding = (const float*)d_in[3];
    const float* a         = (const float*)d_in[4];
    float* out = (float*)d_out;

    // workspace layout. xb2 overlays slab (slab dead after csr_build_conv,
    // xb2 first written in layer-2 spmm — stream-ordered, safe).
    int2* slab     = (int2*)d_ws;                                  // 12.8 MB
    unsigned* csr4 = (unsigned*)(slab + (size_t)NB * CAP);         // 3.2 MB
    __hip_bfloat162* xbE = (__hip_bfloat162*)(csr4 + N_EDGES);     // 10 MB
    __hip_bfloat162* xb1 = xbE + (size_t)N_NODES * HALF_EMB;       // 10 MB
    float* norms = (float*)(xb1 + (size_t)N_NODES * HALF_EMB);     // 3*50,000
    int* row_ptr    = (int*)(norms + 3 * N_NODES);                 // 50,001
    int* bucket_cnt = row_ptr + (N_NODES + 1);                     // NB
    __hip_bfloat162* xb2 = (__hip_bfloat162*)slab;                 // overlay

    const int node_blocks = (N_NODES + 3) / 4;          // 4 waves / block
    const int part_blocks = (N_EDGES + EPB - 1) / EPB;  // 196

    // ---- CSR build: partition -> (per-bucket sort + emb prep, one dispatch) ----
    hipMemsetAsync(bucket_cnt, 0, sizeof(int) * NB, stream);
    bucket_scatter<<<part_blocks, 256, 0, stream>>>(adj_row, adj_col, adj_val,
                                                    bucket_cnt, slab);
    csr_build_conv<<<NB + CONV_BLOCKS, 256, 0, stream>>>(bucket_cnt, slab, csr4,
                                                         row_ptr, embedding,
                                                         norms, xbE);

    // ---- layer 1, 2 (raw bf16 + norm), layer 3 (fused epilogue) ----
    spmm_fused<<<node_blocks, 256, 0, stream>>>(row_ptr, csr4, (const unsigned*)xbE,
                                                xb1, norms + N_NODES, a,
                                                nullptr, nullptr, nullptr,
                                                nullptr, 0);
    spmm_fused<<<node_blocks, 256, 0, stream>>>(row_ptr, csr4, (const unsigned*)xb1,
                                                xb2, norms + 2 * N_NODES, a,
                                                nullptr, nullptr, nullptr,
                                                nullptr, 0);
    spmm_fused<<<node_blocks, 256, 0, stream>>>(row_ptr, csr4, (const unsigned*)xb2,
                                                nullptr, nullptr, a,
                                                xbE, xb1, norms,
                                                out, 1);
}

// Round 11
// 216.926 us; speedup vs baseline: 1.3417x; 1.0358x over previous
//
#include <hip/hip_runtime.h>
#include <hip/hip_bf16.h>

#define N_NODES 50000
#define N_EDGES 800000
#define EMB 100
#define HALF_EMB 50
#define QEMB 25
#define NORM_EPS 1e-12f
#define BROWS 128                      // rows per bucket
#define NB ((N_NODES + BROWS - 1) / BROWS)   // 391 buckets
#define CAP 4096                       // slab capacity per bucket (avg fill ~2046)
#define EPB 4096                       // edges per partition block -> run len ~10.5

#define CONV_BLOCKS ((N_NODES + 3) / 4)      // 12500 (4 waves/block)

// Pass 1: block-level radix partition into NB coarse buckets (196 blocks).
// Slab record: ((row<<16)|col, fp32 val bits).
__global__ void bucket_scatter(const int* __restrict__ adj_row,
                               const int* __restrict__ adj_col,
                               const float* __restrict__ adj_val,
                               int* __restrict__ bucket_cnt,
                               int2* __restrict__ slab) {
    __shared__ int hist[NB];
    __shared__ int cur[NB];     // becomes write cursor (= reserved global base)
    const int t = threadIdx.x;
    const int base_e = blockIdx.x * EPB;
    for (int i = t; i < NB; i += 256) hist[i] = 0;
    __syncthreads();
    int rows[EPB / 256];
    #pragma unroll
    for (int j = 0; j < EPB / 256; ++j) {
        int e = base_e + j * 256 + t;
        int r = (e < N_EDGES) ? adj_row[e] : -1;
        rows[j] = r;
        if (r >= 0) atomicAdd(&hist[r >> 7], 1);
    }
    __syncthreads();
    for (int i = t; i < NB; i += 256) {
        int c = hist[i];
        cur[i] = (c > 0) ? atomicAdd(&bucket_cnt[i], c) : 0;
    }
    __syncthreads();
    #pragma unroll
    for (int j = 0; j < EPB / 256; ++j) {
        int e = base_e + j * 256 + t;
        int r = rows[j];
        if (r >= 0) {
            int b = r >> 7;
            int p = atomicAdd(&cur[b], 1);
            unsigned rc = ((unsigned)r << 16) | (unsigned)adj_col[e];
            slab[(size_t)b * CAP + p] = make_int2((int)rc, __float_as_int(adj_val[e]));
        }
    }
}

// Pass 2 (merged dispatch):
//   blocks [0, NB)            : per-bucket counting sort -> compressed CSR + row_ptr
//   blocks [NB, NB+CONV_BLOCKS): conv_emb (bf16 cast + row norms of embedding)
__global__ void csr_build_conv(const int* __restrict__ bucket_cnt,
                               const int2* __restrict__ slab,
                               unsigned* __restrict__ csr4,
                               int* __restrict__ row_ptr,
                               const float* __restrict__ emb,
                               float* __restrict__ norm0,
                               __hip_bfloat162* __restrict__ xb) {
    __shared__ int2 eds[CAP];
    __shared__ int hist[BROWS];   // later reused as scatter cursor
    __shared__ int incl[BROWS];
    __shared__ int red[256];
    const int t = threadIdx.x;
    if (blockIdx.x >= NB) {
        // ---- conv_emb part ----
        int wave = (blockIdx.x - NB) * 4 + (t >> 6);
        int lane = t & 63;
        if (wave >= N_NODES) return;
        float2 v = make_float2(0.0f, 0.0f);
        size_t idx = (size_t)wave * HALF_EMB + lane;
        if (lane < HALF_EMB) v = ((const float2*)emb)[idx];
        float s = v.x * v.x + v.y * v.y;
        #pragma unroll
        for (int off = 32; off > 0; off >>= 1) s += __shfl_xor(s, off);
        if (lane == 0) norm0[wave] = sqrtf(s);
        if (lane < HALF_EMB) {
            __hip_bfloat162 b;
            b.x = __float2bfloat16(v.x);
            b.y = __float2bfloat16(v.y);
            xb[idx] = b;
        }
        return;
    }
    // ---- csr_build part ----
    const int b = blockIdx.x;
    // embedded exclusive prefix: base = sum_{i<b} cnt[i]
    int part = 0;
    for (int i = t; i < b; i += 256) part += bucket_cnt[i];
    red[t] = part;
    __syncthreads();
    #pragma unroll
    for (int off = 128; off > 0; off >>= 1) {
        if (t < off) red[t] += red[t + off];
        __syncthreads();
    }
    const int base = red[0];
    const int cnt = bucket_cnt[b];
    for (int i = t; i < cnt; i += 256) eds[i] = slab[(size_t)b * CAP + i];
    if (t < BROWS) hist[t] = 0;
    __syncthreads();
    for (int i = t; i < cnt; i += 256)
        atomicAdd(&hist[(int)(((unsigned)eds[i].x) >> 16) & (BROWS - 1)], 1);
    __syncthreads();
    int v = (t < BROWS) ? hist[t] : 0;
    if (t < BROWS) incl[t] = v;
    __syncthreads();
    #pragma unroll
    for (int off = 1; off < BROWS; off <<= 1) {
        int n = (t >= off && t < BROWS) ? incl[t - off] : 0;
        __syncthreads();
        if (t < BROWS) incl[t] += n;
        __syncthreads();
    }
    int ex = (t < BROWS) ? (incl[t] - v) : 0;
    __syncthreads();
    if (t < BROWS) hist[t] = ex;          // cursor init
    int gr = b * BROWS + t;
    if (t < BROWS && gr < N_NODES) row_ptr[gr] = base + ex;
    if (b == 0 && t == 0) row_ptr[N_NODES] = N_EDGES;
    __syncthreads();
    for (int i = t; i < cnt; i += 256) {
        int2 e = eds[i];
        int l = (int)(((unsigned)e.x) >> 16) & (BROWS - 1);
        int p = atomicAdd(&hist[l], 1);
        unsigned col = (unsigned)e.x & 0xFFFFu;
        __hip_bfloat16 hv = __float2bfloat16(__int_as_float(e.y));
        unsigned vb = (unsigned)*reinterpret_cast<unsigned short*>(&hv);
        csr4[base + p] = (col << 16) | vb;
    }
}

// unpack 4 bf16 (uint2) -> float4, bit-twiddle only
__device__ inline float4 up4(uint2 u) {
    float4 f;
    f.x = __uint_as_float(u.x << 16);
    f.y = __uint_as_float(u.x & 0xFFFF0000u);
    f.z = __uint_as_float(u.y << 16);
    f.w = __uint_as_float(u.y & 0xFFFF0000u);
    return f;
}

// SpMM pair-gather: half-wave h=lane>>5 owns edge d+h; lane (h,c<25) loads
// uint2 = 4 bf16 features [4c..4c+4) of its edge's source row -> one VMEM
// instruction covers TWO edges. Records broadcast with a single
// divergent-source shfl. Pad lanes have rec=0 => v=0 (tail-safe).
// rec = col<<16 | bf16(val): col = rec>>16, val = bits(rec<<16) (exact).
__global__ void spmm_fused(const int* __restrict__ row_ptr,
                           const unsigned* __restrict__ csr4,
                           const uint2* __restrict__ xb,
                           uint2* __restrict__ yb,
                           float* __restrict__ norm_out,
                           const float* __restrict__ a,
                           const uint2* __restrict__ ep0,
                           const uint2* __restrict__ ep1,
                           const float* __restrict__ norms,
                           float* __restrict__ out,
                           int final_layer) {
    int wave = blockIdx.x * (blockDim.x >> 6) + (threadIdx.x >> 6);
    int lane = threadIdx.x & 63;
    if (wave >= N_NODES) return;
    int start = row_ptr[wave];
    int end   = row_ptr[wave + 1];
    int deg   = end - start;
    unsigned myrec = (lane < deg) ? csr4[start + lane] : 0u;
    int h = lane >> 5, c = lane & 31;
    bool act = (c < QEMB);
    float4 acc = make_float4(0.0f, 0.0f, 0.0f, 0.0f);
    int dn  = (deg < 64) ? deg : 64;
    int dn2 = (dn + 1) & ~1;           // round up to pairs (pad recs are 0)
    int d = 0;
    for (; d + 8 <= dn2; d += 8) {     // 4 gathers : 8 edges
        unsigned ra = __shfl(myrec, d + h);
        unsigned rb = __shfl(myrec, d + 2 + h);
        unsigned rc = __shfl(myrec, d + 4 + h);
        unsigned rd = __shfl(myrec, d + 6 + h);
        if (act) {
            uint2 ua = xb[(size_t)(ra >> 16) * QEMB + c];
            uint2 ub = xb[(size_t)(rb >> 16) * QEMB + c];
            uint2 uc = xb[(size_t)(rc >> 16) * QEMB + c];
            uint2 ud = xb[(size_t)(rd >> 16) * QEMB + c];
            float va = __uint_as_float(ra << 16);
            float vb = __uint_as_float(rb << 16);
            float vc = __uint_as_float(rc << 16);
            float vd = __uint_as_float(rd << 16);
            float4 fa = up4(ua), fb = up4(ub), fc = up4(uc), fd = up4(ud);
            acc.x += va * fa.x; acc.y += va * fa.y; acc.z += va * fa.z; acc.w += va * fa.w;
            acc.x += vb * fb.x; acc.y += vb * fb.y; acc.z += vb * fb.z; acc.w += vb * fb.w;
            acc.x += vc * fc.x; acc.y += vc * fc.y; acc.z += vc * fc.z; acc.w += vc * fc.w;
            acc.x += vd * fd.x; acc.y += vd * fd.y; acc.z += vd * fd.z; acc.w += vd * fd.w;
        }
    }
    for (; d < dn2; d += 2) {
        unsigned r = __shfl(myrec, d + h);
        if (act) {
            uint2 u = xb[(size_t)(r >> 16) * QEMB + c];
            float v = __uint_as_float(r << 16);
            float4 f = up4(u);
            acc.x += v * f.x; acc.y += v * f.y; acc.z += v * f.z; acc.w += v * f.w;
        }
    }
    // overflow fallback (deg > 64): pairs, h selects edge
    for (int e = start + 64; e < end; e += 2) {
        unsigned r = (e + h < end) ? csr4[e + h] : 0u;
        if (act) {
            uint2 u = xb[(size_t)(r >> 16) * QEMB + c];
            float v = __uint_as_float(r << 16);
            float4 f = up4(u);
            acc.x += v * f.x; acc.y += v * f.y; acc.z += v * f.z; acc.w += v * f.w;
        }
    }
    // combine halves: both halves end with full row sums
    acc.x += __shfl_xor(acc.x, 32);
    acc.y += __shfl_xor(acc.y, 32);
    acc.z += __shfl_xor(acc.z, 32);
    acc.w += __shfl_xor(acc.w, 32);
    float s = 0.0f;
    if (h == 0 && act)
        s = acc.x * acc.x + acc.y * acc.y + acc.z * acc.z + acc.w * acc.w;
    #pragma unroll
    for (int off = 32; off > 0; off >>= 1) s += __shfl_xor(s, off);
    if (!final_layer) {
        if (h == 0 && act) {
            __hip_bfloat16 b0 = __float2bfloat16(acc.x);
            __hip_bfloat16 b1 = __float2bfloat16(acc.y);
            __hip_bfloat16 b2 = __float2bfloat16(acc.z);
            __hip_bfloat16 b3 = __float2bfloat16(acc.w);
            uint2 o;
            o.x = (unsigned)*(unsigned short*)&b0 | ((unsigned)*(unsigned short*)&b1 << 16);
            o.y = (unsigned)*(unsigned short*)&b2 | ((unsigned)*(unsigned short*)&b3 << 16);
            yb[(size_t)wave * QEMB + c] = o;
        }
        if (lane == 0) norm_out[wave] = sqrtf(s);
    } else {
        float s0 = a[0] / fmaxf(norms[wave], NORM_EPS);
        float s1 = a[1] / fmaxf(norms[N_NODES + wave], NORM_EPS);
        float s2 = a[2] / fmaxf(norms[2 * N_NODES + wave], NORM_EPS);
        float s3 = a[3] / fmaxf(sqrtf(s), NORM_EPS);
        if (h == 0 && act) {
            size_t idx = (size_t)wave * QEMB + c;
            float4 f0 = up4(ep0[idx]);   // bf16(emb)
            float4 f1 = up4(ep1[idx]);   // x1
            float4 f2 = up4(xb[idx]);    // x2 (the gather table, L2-warm)
            float4 o;
            o.x = s0 * f0.x + s1 * f1.x + s2 * f2.x + s3 * acc.x;
            o.y = s0 * f0.y + s1 * f1.y + s2 * f2.y + s3 * acc.y;
            o.z = s0 * f0.z + s1 * f1.z + s2 * f2.z + s3 * acc.z;
            o.w = s0 * f0.w + s1 * f1.w + s2 * f2.w + s3 * acc.w;
            ((float4*)out)[idx] = o;
        }
    }
}

extern "C" void kernel_launch(void* const* d_in, const int* in_sizes, int n_in,
                              void* d_out, int out_size, void* d_ws, size_t ws_size,
                              hipStream_t stream) {
    const int*   adj_row   = (const int*)d_in[0];
    const int*   adj_col   = (const int*)d_in[1];
    const float* adj_val   = (const float*)d_in[2];
    const float* embedding = (const float*)d_in[3];
    const float* a         = (const float*)d_in[4];
    float* out = (float*)d_out;

    // workspace layout. xb2 overlays slab (slab dead after csr_build_conv,
    // xb2 first written in layer-2 spmm — stream-ordered, safe).
    int2* slab     = (int2*)d_ws;                                  // 12.8 MB
    unsigned* csr4 = (unsigned*)(slab + (size_t)NB * CAP);         // 3.2 MB
    uint2* xbE = (uint2*)(csr4 + N_EDGES);                         // 10 MB
    uint2* xb1 = xbE + (size_t)N_NODES * QEMB;                     // 10 MB
    float* norms = (float*)(xb1 + (size_t)N_NODES * QEMB);         // 3*50,000
    int* row_ptr    = (int*)(norms + 3 * N_NODES);                 // 50,001
    int* bucket_cnt = row_ptr + (N_NODES + 1);                     // NB
    uint2* xb2 = (uint2*)slab;                                     // overlay

    const int node_blocks = (N_NODES + 3) / 4;          // 4 waves / block
    const int part_blocks = (N_EDGES + EPB - 1) / EPB;  // 196

    // ---- CSR build: partition -> (per-bucket sort + emb prep, one dispatch) ----
    hipMemsetAsync(bucket_cnt, 0, sizeof(int) * NB, stream);
    bucket_scatter<<<part_blocks, 256, 0, stream>>>(adj_row, adj_col, adj_val,
                                                    bucket_cnt, slab);
    csr_build_conv<<<NB + CONV_BLOCKS, 256, 0, stream>>>(bucket_cnt, slab, csr4,
                                                         row_ptr, embedding,
                                                         norms, (__hip_bfloat162*)xbE);

    // ---- layer 1, 2 (raw bf16 + norm), layer 3 (fused epilogue) ----
    spmm_fused<<<node_blocks, 256, 0, stream>>>(row_ptr, csr4, xbE,
                                                xb1, norms + N_NODES, a,
                                                nullptr, nullptr, nullptr,
                                                nullptr, 0);
    spmm_fused<<<node_blocks, 256, 0, stream>>>(row_ptr, csr4, xb1,
                                                xb2, norms + 2 * N_NODES, a,
                                                nullptr, nullptr, nullptr,
                                                nullptr, 0);
    spmm_fused<<<node_blocks, 256, 0, stream>>>(row_ptr, csr4, xb2,
                                                nullptr, nullptr, a,
                                                xbE, xb1, norms,
                                                out, 1);
}

// Round 12
// 202.001 us; speedup vs baseline: 1.4408x; 1.0739x over previous
//
#include <hip/hip_runtime.h>
#include <hip/hip_bf16.h>

#define N_NODES 50000
#define N_EDGES 800000
#define EMB 100
#define HALF_EMB 50
#define QEMB 25
#define NORM_EPS 1e-12f
#define BROWS 128                      // rows per bucket
#define NB ((N_NODES + BROWS - 1) / BROWS)   // 391 buckets
#define CAP 4096                       // slab capacity per bucket (avg fill ~2046)
#define EPB 4096                       // edges per partition block -> run len ~10.5
#define SCAT_BLOCKS ((N_EDGES + EPB - 1) / EPB)   // 196
#define CONV_BLOCKS 3125               // 16 waves x 3125 = 50000 nodes exactly

// Dispatch A (merged): blocks [0,196) = bucket scatter (1024 thr, 16 waves for
// latency hiding); blocks [196, 196+3125) = conv_emb. Disjoint inputs -> the
// conv blocks use the CUs scatter leaves idle.
__global__ __launch_bounds__(1024) void scatter_conv(
        const int* __restrict__ adj_row, const int* __restrict__ adj_col,
        const float* __restrict__ adj_val, int* __restrict__ bucket_cnt,
        int2* __restrict__ slab,
        const float* __restrict__ emb, float* __restrict__ norm0,
        __hip_bfloat162* __restrict__ xb) {
    const int t = threadIdx.x;
    if (blockIdx.x >= SCAT_BLOCKS) {
        // ---- conv_emb: one wave per node ----
        int wave = (blockIdx.x - SCAT_BLOCKS) * 16 + (t >> 6);
        int lane = t & 63;
        if (wave >= N_NODES) return;
        float2 v = make_float2(0.0f, 0.0f);
        size_t idx = (size_t)wave * HALF_EMB + lane;
        if (lane < HALF_EMB) v = ((const float2*)emb)[idx];
        float s = v.x * v.x + v.y * v.y;
        #pragma unroll
        for (int off = 32; off > 0; off >>= 1) s += __shfl_xor(s, off);
        if (lane == 0) norm0[wave] = sqrtf(s);
        if (lane < HALF_EMB) {
            __hip_bfloat162 b;
            b.x = __float2bfloat16(v.x);
            b.y = __float2bfloat16(v.y);
            xb[idx] = b;
        }
        return;
    }
    // ---- bucket scatter ----
    __shared__ int hist[NB];
    __shared__ int cur[NB];
    const int base_e = blockIdx.x * EPB;
    for (int i = t; i < NB; i += 1024) hist[i] = 0;
    __syncthreads();
    int rows[EPB / 1024];
    #pragma unroll
    for (int j = 0; j < EPB / 1024; ++j) {
        int e = base_e + j * 1024 + t;
        int r = (e < N_EDGES) ? adj_row[e] : -1;
        rows[j] = r;
        if (r >= 0) atomicAdd(&hist[r >> 7], 1);
    }
    __syncthreads();
    for (int i = t; i < NB; i += 1024) {
        int c = hist[i];
        cur[i] = (c > 0) ? atomicAdd(&bucket_cnt[i], c) : 0;
    }
    __syncthreads();
    #pragma unroll
    for (int j = 0; j < EPB / 1024; ++j) {
        int e = base_e + j * 1024 + t;
        int r = rows[j];
        if (r >= 0) {
            int b = r >> 7;
            int p = atomicAdd(&cur[b], 1);
            unsigned rc = ((unsigned)r << 16) | (unsigned)adj_col[e];
            slab[(size_t)b * CAP + p] = make_int2((int)rc, __float_as_int(adj_val[e]));
        }
    }
}

// Dispatch B: per-bucket counting sort (1024 thr) -> compressed CSR + row_ptr.
__global__ __launch_bounds__(1024) void csr_build(
        const int* __restrict__ bucket_cnt, const int2* __restrict__ slab,
        unsigned* __restrict__ csr4, int* __restrict__ row_ptr) {
    __shared__ int2 eds[CAP];
    __shared__ int hist[BROWS];   // later reused as scatter cursor
    __shared__ int incl[BROWS];
    __shared__ int red[1024];
    const int b = blockIdx.x, t = threadIdx.x;
    // embedded exclusive prefix: base = sum_{i<b} cnt[i]  (b < 391 < 1024)
    red[t] = (t < b) ? bucket_cnt[t] : 0;
    __syncthreads();
    #pragma unroll
    for (int off = 512; off > 0; off >>= 1) {
        if (t < off) red[t] += red[t + off];
        __syncthreads();
    }
    const int base = red[0];
    const int cnt = bucket_cnt[b];
    for (int i = t; i < cnt; i += 1024) eds[i] = slab[(size_t)b * CAP + i];
    if (t < BROWS) hist[t] = 0;
    __syncthreads();
    for (int i = t; i < cnt; i += 1024)
        atomicAdd(&hist[(int)(((unsigned)eds[i].x) >> 16) & (BROWS - 1)], 1);
    __syncthreads();
    int v = (t < BROWS) ? hist[t] : 0;
    if (t < BROWS) incl[t] = v;
    __syncthreads();
    #pragma unroll
    for (int off = 1; off < BROWS; off <<= 1) {
        int n = (t >= off && t < BROWS) ? incl[t - off] : 0;
        __syncthreads();
        if (t < BROWS) incl[t] += n;
        __syncthreads();
    }
    int ex = (t < BROWS) ? (incl[t] - v) : 0;
    __syncthreads();
    if (t < BROWS) hist[t] = ex;          // cursor init
    int gr = b * BROWS + t;
    if (t < BROWS && gr < N_NODES) row_ptr[gr] = base + ex;
    if (b == 0 && t == 0) row_ptr[N_NODES] = N_EDGES;
    __syncthreads();
    for (int i = t; i < cnt; i += 1024) {
        int2 e = eds[i];
        int l = (int)(((unsigned)e.x) >> 16) & (BROWS - 1);
        int p = atomicAdd(&hist[l], 1);
        unsigned col = (unsigned)e.x & 0xFFFFu;
        __hip_bfloat16 hv = __float2bfloat16(__int_as_float(e.y));
        unsigned vb = (unsigned)*reinterpret_cast<unsigned short*>(&hv);
        csr4[base + p] = (col << 16) | vb;
    }
}

// unpack 4 bf16 (uint2) -> float4, bit-twiddle only
__device__ inline float4 up4(uint2 u) {
    float4 f;
    f.x = __uint_as_float(u.x << 16);
    f.y = __uint_as_float(u.x & 0xFFFF0000u);
    f.z = __uint_as_float(u.y << 16);
    f.w = __uint_as_float(u.y & 0xFFFF0000u);
    return f;
}

// SpMM pair-gather: half-wave h=lane>>5 owns edge d+h; lane (h,c<25) loads
// uint2 = 4 bf16 features of its edge's source row. Records broadcast with a
// single divergent-source shfl. Pad lanes have rec=0 => v=0 (tail-safe).
// rec = col<<16 | bf16(val): col = rec>>16, val = bits(rec<<16) (exact).
__global__ void spmm_fused(const int* __restrict__ row_ptr,
                           const unsigned* __restrict__ csr4,
                           const uint2* __restrict__ xb,
                           uint2* __restrict__ yb,
                           float* __restrict__ norm_out,
                           const float* __restrict__ a,
                           const uint2* __restrict__ ep0,
                           const uint2* __restrict__ ep1,
                           const float* __restrict__ norms,
                           float* __restrict__ out,
                           int final_layer) {
    int wave = blockIdx.x * (blockDim.x >> 6) + (threadIdx.x >> 6);
    int lane = threadIdx.x & 63;
    if (wave >= N_NODES) return;
    int start = row_ptr[wave];
    int end   = row_ptr[wave + 1];
    int deg   = end - start;
    unsigned myrec = (lane < deg) ? csr4[start + lane] : 0u;
    int h = lane >> 5, c = lane & 31;
    bool act = (c < QEMB);
    float4 acc = make_float4(0.0f, 0.0f, 0.0f, 0.0f);
    int dn  = (deg < 64) ? deg : 64;
    int dn2 = (dn + 1) & ~1;           // round up to pairs (pad recs are 0)
    int d = 0;
    for (; d + 8 <= dn2; d += 8) {     // 4 gathers : 8 edges
        unsigned ra = __shfl(myrec, d + h);
        unsigned rb = __shfl(myrec, d + 2 + h);
        unsigned rc = __shfl(myrec, d + 4 + h);
        unsigned rd = __shfl(myrec, d + 6 + h);
        if (act) {
            uint2 ua = xb[(size_t)(ra >> 16) * QEMB + c];
            uint2 ub = xb[(size_t)(rb >> 16) * QEMB + c];
            uint2 uc = xb[(size_t)(rc >> 16) * QEMB + c];
            uint2 ud = xb[(size_t)(rd >> 16) * QEMB + c];
            float va = __uint_as_float(ra << 16);
            float vb = __uint_as_float(rb << 16);
            float vc = __uint_as_float(rc << 16);
            float vd = __uint_as_float(rd << 16);
            float4 fa = up4(ua), fb = up4(ub), fc = up4(uc), fd = up4(ud);
            acc.x += va * fa.x; acc.y += va * fa.y; acc.z += va * fa.z; acc.w += va * fa.w;
            acc.x += vb * fb.x; acc.y += vb * fb.y; acc.z += vb * fb.z; acc.w += vb * fb.w;
            acc.x += vc * fc.x; acc.y += vc * fc.y; acc.z += vc * fc.z; acc.w += vc * fc.w;
            acc.x += vd * fd.x; acc.y += vd * fd.y; acc.z += vd * fd.z; acc.w += vd * fd.w;
        }
    }
    for (; d < dn2; d += 2) {
        unsigned r = __shfl(myrec, d + h);
        if (act) {
            uint2 u = xb[(size_t)(r >> 16) * QEMB + c];
            float v = __uint_as_float(r << 16);
            float4 f = up4(u);
            acc.x += v * f.x; acc.y += v * f.y; acc.z += v * f.z; acc.w += v * f.w;
        }
    }
    // overflow fallback (deg > 64): pairs, h selects edge
    for (int e = start + 64; e < end; e += 2) {
        unsigned r = (e + h < end) ? csr4[e + h] : 0u;
        if (act) {
            uint2 u = xb[(size_t)(r >> 16) * QEMB + c];
            float v = __uint_as_float(r << 16);
            float4 f = up4(u);
            acc.x += v * f.x; acc.y += v * f.y; acc.z += v * f.z; acc.w += v * f.w;
        }
    }
    // combine halves: both halves end with full row sums
    acc.x += __shfl_xor(acc.x, 32);
    acc.y += __shfl_xor(acc.y, 32);
    acc.z += __shfl_xor(acc.z, 32);
    acc.w += __shfl_xor(acc.w, 32);
    float s = 0.0f;
    if (h == 0 && act)
        s = acc.x * acc.x + acc.y * acc.y + acc.z * acc.z + acc.w * acc.w;
    #pragma unroll
    for (int off = 32; off > 0; off >>= 1) s += __shfl_xor(s, off);
    if (!final_layer) {
        if (h == 0 && act) {
            __hip_bfloat16 b0 = __float2bfloat16(acc.x);
            __hip_bfloat16 b1 = __float2bfloat16(acc.y);
            __hip_bfloat16 b2 = __float2bfloat16(acc.z);
            __hip_bfloat16 b3 = __float2bfloat16(acc.w);
            uint2 o;
            o.x = (unsigned)*(unsigned short*)&b0 | ((unsigned)*(unsigned short*)&b1 << 16);
            o.y = (unsigned)*(unsigned short*)&b2 | ((unsigned)*(unsigned short*)&b3 << 16);
            yb[(size_t)wave * QEMB + c] = o;
        }
        if (lane == 0) norm_out[wave] = sqrtf(s);
    } else {
        float s0 = a[0] / fmaxf(norms[wave], NORM_EPS);
        float s1 = a[1] / fmaxf(norms[N_NODES + wave], NORM_EPS);
        float s2 = a[2] / fmaxf(norms[2 * N_NODES + wave], NORM_EPS);
        float s3 = a[3] / fmaxf(sqrtf(s), NORM_EPS);
        if (h == 0 && act) {
            size_t idx = (size_t)wave * QEMB + c;
            float4 f0 = up4(ep0[idx]);   // bf16(emb)
            float4 f1 = up4(ep1[idx]);   // x1
            float4 f2 = up4(xb[idx]);    // x2 (the gather table, L2-warm)
            float4 o;
            o.x = s0 * f0.x + s1 * f1.x + s2 * f2.x + s3 * acc.x;
            o.y = s0 * f0.y + s1 * f1.y + s2 * f2.y + s3 * acc.y;
            o.z = s0 * f0.z + s1 * f1.z + s2 * f2.z + s3 * acc.z;
            o.w = s0 * f0.w + s1 * f1.w + s2 * f2.w + s3 * acc.w;
            ((float4*)out)[idx] = o;
        }
    }
}

extern "C" void kernel_launch(void* const* d_in, const int* in_sizes, int n_in,
                              void* d_out, int out_size, void* d_ws, size_t ws_size,
                              hipStream_t stream) {
    const int*   adj_row   = (const int*)d_in[0];
    const int*   adj_col   = (const int*)d_in[1];
    const float* adj_val   = (const float*)d_in[2];
    const float* embedding = (const float*)d_in[3];
    const float* a         = (const float*)d_in[4];
    float* out = (float*)d_out;

    // workspace layout. xb2 overlays slab (slab dead after csr_build,
    // xb2 first written in layer-2 spmm — stream-ordered, safe).
    int2* slab     = (int2*)d_ws;                                  // 12.8 MB
    unsigned* csr4 = (unsigned*)(slab + (size_t)NB * CAP);         // 3.2 MB
    uint2* xbE = (uint2*)(csr4 + N_EDGES);                         // 10 MB
    uint2* xb1 = xbE + (size_t)N_NODES * QEMB;                     // 10 MB
    float* norms = (float*)(xb1 + (size_t)N_NODES * QEMB);         // 3*50,000
    int* row_ptr    = (int*)(norms + 3 * N_NODES);                 // 50,001
    int* bucket_cnt = row_ptr + (N_NODES + 1);                     // NB
    uint2* xb2 = (uint2*)slab;                                     // overlay

    const int node_blocks = (N_NODES + 3) / 4;          // 4 waves / block

    // ---- CSR build: (scatter || emb prep) -> per-bucket sort ----
    hipMemsetAsync(bucket_cnt, 0, sizeof(int) * NB, stream);
    scatter_conv<<<SCAT_BLOCKS + CONV_BLOCKS, 1024, 0, stream>>>(
        adj_row, adj_col, adj_val, bucket_cnt, slab,
        embedding, norms, (__hip_bfloat162*)xbE);
    csr_build<<<NB, 1024, 0, stream>>>(bucket_cnt, slab, csr4, row_ptr);

    // ---- layer 1, 2 (raw bf16 + norm), layer 3 (fused epilogue) ----
    spmm_fused<<<node_blocks, 256, 0, stream>>>(row_ptr, csr4, xbE,
                                                xb1, norms + N_NODES, a,
                                                nullptr, nullptr, nullptr,
                                                nullptr, 0);
    spmm_fused<<<node_blocks, 256, 0, stream>>>(row_ptr, csr4, xb1,
                                                xb2, norms + 2 * N_NODES, a,
                                                nullptr, nullptr, nullptr,
                                                nullptr, 0);
    spmm_fused<<<node_blocks, 256, 0, stream>>>(row_ptr, csr4, xb2,
                                                nullptr, nullptr, a,
                                                xbE, xb1, norms,
                                                out, 1);
}